// Round 1
// baseline (248.600 us; speedup 1.0000x reference)
//
#include <hip/hip_runtime.h>
#include <hip/hip_bf16.h>

#define M_ 2
#define D_ 128
#define NI_ 131072
#define L_ 4
#define NPL_ 2048
#define R_ 8
#define T_ 32
#define N_ (NI_ + L_ * NPL_)   // 139264
#define ND_ (L_ * NPL_)        // 8192 deriv nodes
#define EV_TILES (N_ / 64)     // 2176

typedef __bf16 bf16x8 __attribute__((ext_vector_type(8)));
typedef float f32x4 __attribute__((ext_vector_type(4)));

// ---- ws layout (bytes) ----
#define OFF_W1T    0u            // [M][R][128(dout)][256(c)] bf16 = 1048576
#define OFF_W2T    1048576u      // [M][R][128(e)][128(d)] bf16  = 524288
#define OFF_WE1T   1572864u      // [M][128(e)][128(d)] bf16     = 65536
#define OFF_TAB    1638400u      // [M][T][128] bf16             = 16384
#define OFF_SVEC   1654784u      // [M][128] bf16                = 512
#define OFF_SORTED 1655296u      // [L][2048] int                = 32768
#define OFF_STARTS 1688064u      // [L][8] int                   = 128
#define OFF_COUNTS 1688192u      // [L][8] int                   = 128
#define OFF_PA     1688320u      // [M][2176] f32                = 17408
#define OFF_PB     1705728u
#define OFF_PPOK   1723136u
#define OFF_PNOK   1740544u
#define OFF_PTP    1757952u      // [2176] f32 = 8704
#define OFF_PTN    1766656u
#define OFF_STORE  1775360u      // [M][8192][128] bf16 = 4194304 ; end ~5.97MB

__device__ __forceinline__ unsigned short f2bu(float f) {
  unsigned int u = __float_as_uint(f);
  u += 0x7fffu + ((u >> 16) & 1u);        // RNE (finite values only)
  return (unsigned short)(u >> 16);
}
__device__ __forceinline__ bf16x8 ldb8(const unsigned short* p) {
  return *reinterpret_cast<const bf16x8*>(p);
}

// value of node `row` (global id), 8 consecutive dims starting at d0.
// init nodes are recomputed on the fly (saves 128MB of store traffic).
__device__ __forceinline__ bf16x8 node_chunk(int m, int row, int d0,
    const unsigned short* tab, const unsigned short* svec,
    const unsigned short* sd, const int* thax, const float* sine) {
  if (row < NI_) {
    bf16x8 tv = ldb8(&tab[(m * T_ + thax[row]) * D_ + d0]);
    bf16x8 sv = ldb8(&svec[m * D_ + d0]);
    float sn = sine[row];
    bf16x8 r;
#pragma unroll
    for (int j = 0; j < 8; ++j)
      r[j] = (__bf16)((float)tv[j] + sn * (float)sv[j]);
    return r;
  }
  return ldb8(&sd[(m * ND_ + (row - NI_)) * D_ + d0]);
}

// ---------------- prep: bf16 convert + transpose weights ----------------
__global__ __launch_bounds__(256) void prep_kernel(
    const float* W1, const float* W2, const float* We1,
    const float* init_table, const float* s_vec,
    unsigned short* W1T, unsigned short* W2T, unsigned short* We1T,
    unsigned short* tab, unsigned short* svec) {
  int idx = blockIdx.x * 256 + threadIdx.x;
  const int n1 = M_ * R_ * D_ * 256;   // 524288
  const int n2 = M_ * R_ * D_ * D_;    // 262144
  const int n3 = M_ * D_ * D_;         // 32768
  const int n4 = M_ * T_ * D_;         // 8192
  const int n5 = M_ * D_;              // 256
  if (idx < n1) {
    int c = idx & 255, d = (idx >> 8) & 127, mr = idx >> 15;
    W1T[(mr * D_ + d) * 256 + c] = f2bu(W1[(mr * 256 + c) * D_ + d]);
  } else if (idx < n1 + n2) {
    int o = idx - n1; int d = o & 127, e = (o >> 7) & 127, mr = o >> 14;
    W2T[(mr * D_ + e) * D_ + d] = f2bu(W2[(mr * D_ + d) * D_ + e]);
  } else if (idx < n1 + n2 + n3) {
    int o = idx - n1 - n2; int d = o & 127, e = (o >> 7) & 127, m = o >> 14;
    We1T[(m * D_ + e) * D_ + d] = f2bu(We1[(m * D_ + d) * D_ + e]);
  } else if (idx < n1 + n2 + n3 + n4) {
    int o = idx - n1 - n2 - n3;
    tab[o] = f2bu(init_table[o]);
  } else if (idx < n1 + n2 + n3 + n4 + n5) {
    int o = idx - n1 - n2 - n3 - n4;
    svec[o] = f2bu(s_vec[o]);
  }
}

// ---------------- counting sort of each layer's nodes by rule ----------------
__global__ __launch_bounds__(256) void rsort_kernel(const int* ridx, int* sorted,
                                                    int* starts, int* counts) {
  int l = blockIdx.x;
  __shared__ int cnt[R_], off[R_];
  int tid = threadIdx.x;
  if (tid < R_) cnt[tid] = 0;
  __syncthreads();
  for (int n = tid; n < NPL_; n += 256) atomicAdd(&cnt[ridx[l * NPL_ + n]], 1);
  __syncthreads();
  if (tid == 0) {
    int run = 0;
    for (int r = 0; r < R_; ++r) {
      off[r] = run; starts[l * R_ + r] = run; counts[l * R_ + r] = cnt[r];
      run += cnt[r];
    }
  }
  __syncthreads();
  for (int n = tid; n < NPL_; n += 256) {
    int r = ridx[l * NPL_ + n];
    int p = atomicAdd(&off[r], 1);
    sorted[l * NPL_ + p] = n;   // order within rule irrelevant: per-row math identical
  }
}

// ---------------- one DAG layer: rule-batched 2-layer MLP via MFMA ----------------
// grid (tile=128, r=8, m=2), block = 1 wave (64)
__global__ __launch_bounds__(64) void layer_kernel(int l,
    const int* thax, const float* sine, const int* par,
    const float* b1, const float* b2, const float* tweaks,
    const unsigned short* tab, const unsigned short* svec,
    const unsigned short* W1T, const unsigned short* W2T,
    const int* sorted, const int* starts, const int* counts,
    unsigned short* sd) {
  int tile = blockIdx.x, r = blockIdx.y, m = blockIdx.z;
  int cnt = counts[l * R_ + r];
  int base = tile * 16;
  if (base >= cnt) return;
  int start = starts[l * R_ + r];
  int lane = threadIdx.x;
  int l15 = lane & 15, l4 = lane >> 4;
  int valid = cnt - base; if (valid > 16) valid = 16;
  int loc = base + (l15 < valid ? l15 : valid - 1);        // clamp pad rows
  int node = sorted[l * NPL_ + start + loc];
  int p0 = par[(l * NPL_ + node) * 2 + 0];
  int p1 = par[(l * NPL_ + node) * 2 + 1];
  const unsigned short* w1b = &W1T[(size_t)(m * R_ + r) * D_ * 256];
  const unsigned short* w2b = &W2T[(size_t)(m * R_ + r) * D_ * D_];

  f32x4 acch[8];
#pragma unroll
  for (int f = 0; f < 8; ++f) acch[f] = (f32x4){0.f, 0.f, 0.f, 0.f};
  // h = relu(cat @ W1 + b1): A rows = nodes (lane&15), K = 256 (two parents)
#pragma unroll
  for (int kc = 0; kc < 8; ++kc) {
    int k = kc * 32 + l4 * 8;
    int p = (k < 128) ? p0 : p1;
    bf16x8 a = node_chunk(m, p, k & 127, tab, svec, sd, thax, sine);
#pragma unroll
    for (int f = 0; f < 8; ++f) {
      bf16x8 b = ldb8(&w1b[(f * 16 + l15) * 256 + k]);
      acch[f] = __builtin_amdgcn_mfma_f32_16x16x32_bf16(a, b, acch[f], 0, 0, 0);
    }
  }
  // C-layout -> A-layout round trip through swizzled LDS
  __shared__ unsigned short h_lds[16 * 128];
  const float* b1v = &b1[(m * R_ + r) * D_];
#pragma unroll
  for (int f = 0; f < 8; ++f) {
    int d = f * 16 + l15;
    float bb = b1v[d];
#pragma unroll
    for (int i = 0; i < 4; ++i) {
      int row = l4 * 4 + i;
      float h = acch[f][i] + bb;
      h = h > 0.f ? h : 0.f;
      h_lds[row * 128 + (d ^ ((row & 7) << 3))] = f2bu(h);
    }
  }
  __syncthreads();
  f32x4 acco[8];
#pragma unroll
  for (int f = 0; f < 8; ++f) acco[f] = (f32x4){0.f, 0.f, 0.f, 0.f};
#pragma unroll
  for (int kc = 0; kc < 4; ++kc) {
    int d0 = kc * 32 + l4 * 8;
    int row = l15;
    bf16x8 a2 = ldb8(&h_lds[row * 128 + (d0 ^ ((row & 7) << 3))]);
#pragma unroll
    for (int f = 0; f < 8; ++f) {
      bf16x8 b = ldb8(&w2b[(f * 16 + l15) * D_ + d0]);
      acco[f] = __builtin_amdgcn_mfma_f32_16x16x32_bf16(a2, b, acco[f], 0, 0, 0);
    }
  }
  float tw1 = tweaks[m * 2 + 1];
  const float* b2v = &b2[(m * R_ + r) * D_];
#pragma unroll
  for (int i = 0; i < 4; ++i) {
    int row = l4 * 4 + i;
    if (row < valid) {
      int nd = sorted[l * NPL_ + start + base + row];
      unsigned short* dst = &sd[(size_t)(m * ND_ + l * NPL_ + nd) * D_];
#pragma unroll
      for (int f = 0; f < 8; ++f) {
        int e = f * 16 + l15;
        dst[e] = f2bu(acco[f][i] + b2v[e] + tw1);
      }
    }
  }
}

// ---------------- eval net + fused BCE partials ----------------
// grid (tile=2176, m=2), block 256 = 4 waves x 16 rows
__global__ __launch_bounds__(256) void eval_kernel(
    const int* thax, const float* sine, const float* pos, const float* neg,
    const float* be1, const float* we2, const float* be2, const float* tweaks,
    const unsigned short* tab, const unsigned short* svec,
    const unsigned short* We1T, const unsigned short* sd,
    float* pA, float* pB, float* pPok, float* pNok, float* pTp, float* pTn) {
  int tile = blockIdx.x, m = blockIdx.y;
  int tid = threadIdx.x;
  int w = tid >> 6, lane = tid & 63;
  int l15 = lane & 15, l4 = lane >> 4;
  int rbase = tile * 64 + w * 16;
  int arow = rbase + l15;

  bf16x8 a[4];
#pragma unroll
  for (int kc = 0; kc < 4; ++kc)
    a[kc] = node_chunk(m, arow, kc * 32 + l4 * 8, tab, svec, sd, thax, sine);

  f32x4 acc[8];
#pragma unroll
  for (int f = 0; f < 8; ++f) acc[f] = (f32x4){0.f, 0.f, 0.f, 0.f};
#pragma unroll
  for (int kc = 0; kc < 4; ++kc) {
#pragma unroll
    for (int f = 0; f < 8; ++f) {
      bf16x8 b = ldb8(&We1T[(m * D_ + f * 16 + l15) * D_ + kc * 32 + l4 * 8]);
      acc[f] = __builtin_amdgcn_mfma_f32_16x16x32_bf16(a[kc], b, acc[f], 0, 0, 0);
    }
  }
  // he = relu(acc + be1); partial logit = sum_e he*we2
  float part[4] = {0.f, 0.f, 0.f, 0.f};
#pragma unroll
  for (int f = 0; f < 8; ++f) {
    int e = f * 16 + l15;
    float bb = be1[m * D_ + e];
    float wv = we2[m * D_ + e];
#pragma unroll
    for (int i = 0; i < 4; ++i) {
      float he = acc[f][i] + bb;
      he = he > 0.f ? he : 0.f;
      part[i] += he * wv;
    }
  }
#pragma unroll
  for (int mask = 1; mask < 16; mask <<= 1) {
#pragma unroll
    for (int i = 0; i < 4; ++i) part[i] += __shfl_xor(part[i], mask, 64);
  }
  __shared__ float red[6][16];
  if (l15 == 0) {                 // leader lanes 0,16,32,48: own rows rbase+l4*4+i
    float tw0 = tweaks[m * 2 + 0];
    float bev = be2[m];
    float sa = 0.f, sb = 0.f, spok = 0.f, snok = 0.f, stp = 0.f, stn = 0.f;
#pragma unroll
    for (int i = 0; i < 4; ++i) {
      int row = rbase + l4 * 4 + i;
      float logit = part[i] + bev + tw0;
      float p = pos[row], ng = neg[row];
      float lse = log1pf(__expf(-fabsf(logit)));
      float spn = fmaxf(-logit, 0.f) + lse;   // softplus(-logit)
      float spp = fmaxf(logit, 0.f) + lse;    // softplus(logit)
      sa += p * spn;
      sb += ng * spp;
      if (logit >= 0.f) spok += p; else snok += ng;
      stp += p; stn += ng;
    }
    int slot = w * 4 + l4;
    red[0][slot] = sa;   red[1][slot] = sb;
    red[2][slot] = spok; red[3][slot] = snok;
    red[4][slot] = stp;  red[5][slot] = stn;
  }
  __syncthreads();
  if (tid == 0) {
    float t[6];
#pragma unroll
    for (int q = 0; q < 6; ++q) {
      float s = 0.f;
      for (int k = 0; k < 16; ++k) s += red[q][k];
      t[q] = s;
    }
    pA[m * EV_TILES + tile] = t[0];
    pB[m * EV_TILES + tile] = t[1];
    pPok[m * EV_TILES + tile] = t[2];
    pNok[m * EV_TILES + tile] = t[3];
    if (m == 0) { pTp[tile] = t[4]; pTn[tile] = t[5]; }
  }
}

// ---------------- deterministic final reduction ----------------
__global__ __launch_bounds__(256) void finalize_kernel(
    const float* pA, const float* pB, const float* pPok, const float* pNok,
    const float* pTp, const float* pTn, float* out) {
  __shared__ float red[256];
  __shared__ float totals[10];
  const float* srcs[10] = {pA, pA + EV_TILES, pB, pB + EV_TILES,
                           pPok, pPok + EV_TILES, pNok, pNok + EV_TILES,
                           pTp, pTn};
  int tid = threadIdx.x;
  for (int q = 0; q < 10; ++q) {
    float s = 0.f;
    for (int i = tid; i < EV_TILES; i += 256) s += srcs[q][i];
    red[tid] = s;
    __syncthreads();
    if (tid == 0) {
      float t = 0.f;
      for (int k = 0; k < 256; ++k) t += red[k];
      totals[q] = t;
    }
    __syncthreads();
  }
  if (tid == 0) {
    float tp = totals[8], tn = totals[9];
    float pw = tn / tp;
    out[0] = pw * totals[0] + totals[2];   // loss m0
    out[1] = pw * totals[1] + totals[3];   // loss m1
    out[2] = totals[4]; out[3] = totals[5]; // posOK
    out[4] = totals[6]; out[5] = totals[7]; // negOK
    out[6] = tp; out[7] = tn;
  }
}

extern "C" void kernel_launch(void* const* d_in, const int* in_sizes, int n_in,
                              void* d_out, int out_size, void* d_ws, size_t ws_size,
                              hipStream_t stream) {
  const int*   thax = (const int*)d_in[0];
  const float* sine = (const float*)d_in[1];
  const int*   par  = (const int*)d_in[2];
  const int*   ridx = (const int*)d_in[3];
  const float* pos  = (const float*)d_in[4];
  const float* neg  = (const float*)d_in[5];
  const float* init_table = (const float*)d_in[6];
  const float* s_vec = (const float*)d_in[7];
  const float* W1 = (const float*)d_in[8];
  const float* b1 = (const float*)d_in[9];
  const float* W2 = (const float*)d_in[10];
  const float* b2 = (const float*)d_in[11];
  const float* tweaks = (const float*)d_in[12];
  const float* We1 = (const float*)d_in[13];
  const float* be1 = (const float*)d_in[14];
  const float* we2 = (const float*)d_in[15];
  const float* be2 = (const float*)d_in[16];

  char* ws = (char*)d_ws;
  unsigned short* W1T  = (unsigned short*)(ws + OFF_W1T);
  unsigned short* W2T  = (unsigned short*)(ws + OFF_W2T);
  unsigned short* We1T = (unsigned short*)(ws + OFF_WE1T);
  unsigned short* tab  = (unsigned short*)(ws + OFF_TAB);
  unsigned short* svec = (unsigned short*)(ws + OFF_SVEC);
  int* sorted = (int*)(ws + OFF_SORTED);
  int* starts = (int*)(ws + OFF_STARTS);
  int* counts = (int*)(ws + OFF_COUNTS);
  float* pA   = (float*)(ws + OFF_PA);
  float* pB   = (float*)(ws + OFF_PB);
  float* pPok = (float*)(ws + OFF_PPOK);
  float* pNok = (float*)(ws + OFF_PNOK);
  float* pTp  = (float*)(ws + OFF_PTP);
  float* pTn  = (float*)(ws + OFF_PTN);
  unsigned short* sd = (unsigned short*)(ws + OFF_STORE);

  prep_kernel<<<3233, 256, 0, stream>>>(W1, W2, We1, init_table, s_vec,
                                        W1T, W2T, We1T, tab, svec);
  rsort_kernel<<<L_, 256, 0, stream>>>(ridx, sorted, starts, counts);
  for (int l = 0; l < L_; ++l) {
    layer_kernel<<<dim3(NPL_ / 16, R_, M_), 64, 0, stream>>>(
        l, thax, sine, par, b1, b2, tweaks, tab, svec, W1T, W2T,
        sorted, starts, counts, sd);
  }
  eval_kernel<<<dim3(EV_TILES, M_), 256, 0, stream>>>(
      thax, sine, pos, neg, be1, we2, be2, tweaks, tab, svec, We1T, sd,
      pA, pB, pPok, pNok, pTp, pTn);
  finalize_kernel<<<1, 256, 0, stream>>>(pA, pB, pPok, pNok, pTp, pTn,
                                         (float*)d_out);
}

// Round 2
// 187.338 us; speedup vs baseline: 1.3270x; 1.3270x over previous
//
#include <hip/hip_runtime.h>
#include <hip/hip_bf16.h>

#define M_ 2
#define D_ 128
#define NI_ 131072
#define L_ 4
#define NPL_ 2048
#define R_ 8
#define T_ 32
#define N_ (NI_ + L_ * NPL_)   // 139264
#define ND_ (L_ * NPL_)        // 8192 deriv nodes
#define PART_ 640              // partial slots per model: 512 init + 128 deriv

typedef __bf16 bf16x8 __attribute__((ext_vector_type(8)));
typedef float f32x4 __attribute__((ext_vector_type(4)));

// ---- ws layout (bytes) ----
#define OFF_W1T    0u            // [M][R][128(d)][256(c)] bf16 = 1048576
#define OFF_W2T    1048576u      // [M][R][128(e)][128(d)] bf16 = 524288
#define OFF_WE1T   1572864u      // [M][128(e)][128(d)] bf16    = 65536
#define OFF_TAB    1638400u      // [M][T][128] bf16            = 16384
#define OFF_SVEC   1654784u      // [M][128] bf16               = 512
#define OFF_SORTED 1655296u      // [L][2048] int               = 32768
#define OFF_STARTS 1688064u      // [L][8] int                  = 128
#define OFF_COUNTS 1688192u      // [L][8] int                  = 128
#define OFF_EA2    1688320u      // [M][64][32][2] f32          = 32768
#define OFF_EWB    1721088u      // [M][128][2] f32             = 2048
#define OFF_PA     1723136u      // [M][640] f32 = 5120
#define OFF_PB     1728256u
#define OFF_PPOK   1733376u
#define OFF_PNOK   1738496u
#define OFF_PTP    1743616u      // [640] f32 = 2560
#define OFF_PTN    1746176u
#define OFF_STORE  1748992u      // [M][8192][128] bf16 = 4194304 ; end ~5.67MB

__device__ __forceinline__ unsigned short f2bu(float f) {
  unsigned int u = __float_as_uint(f);
  u += 0x7fffu + ((u >> 16) & 1u);        // RNE (finite values only)
  return (unsigned short)(u >> 16);
}
__device__ __forceinline__ bf16x8 ldb8(const unsigned short* p) {
  return *reinterpret_cast<const bf16x8*>(p);
}

// value of node `row` (global id), 8 consecutive dims starting at d0.
__device__ __forceinline__ bf16x8 node_chunk(int m, int row, int d0,
    const unsigned short* tab, const unsigned short* svec,
    const unsigned short* sd, const int* thax, const float* sine) {
  if (row < NI_) {
    bf16x8 tv = ldb8(&tab[(m * T_ + thax[row]) * D_ + d0]);
    bf16x8 sv = ldb8(&svec[m * D_ + d0]);
    float sn = sine[row];
    bf16x8 r;
#pragma unroll
    for (int j = 0; j < 8; ++j)
      r[j] = (__bf16)((float)tv[j] + sn * (float)sv[j]);
    return r;
  }
  return ldb8(&sd[(size_t)(m * ND_ + (row - NI_)) * D_ + d0]);
}

// ---------------- prep: LDS-tiled transpose + bf16 convert ----------------
// z: 0..15 -> W1[mr] (src 256x128), 16..31 -> W2[mr] (128x128),
// 32..33 -> We1[m] (128x128), 34 -> tab/svec flat convert
__global__ __launch_bounds__(256) void prep_kernel(
    const float* W1, const float* W2, const float* We1,
    const float* init_table, const float* s_vec,
    unsigned short* W1T, unsigned short* W2T, unsigned short* We1T,
    unsigned short* tab, unsigned short* svec) {
  int z = blockIdx.z;
  int tid = threadIdx.x;
  if (z == 34) {
    if (blockIdx.x || blockIdx.y) return;
    for (int i = tid; i < 8448; i += 256) {
      if (i < 8192) tab[i] = f2bu(init_table[i]);
      else svec[i - 8192] = f2bu(s_vec[i - 8192]);
    }
    return;
  }
  const float* src; unsigned short* dst; int R;
  if (z < 16)      { src = W1  + (size_t)z * 32768;        dst = W1T  + (size_t)z * 32768;        R = 256; }
  else if (z < 32) { src = W2  + (size_t)(z - 16) * 16384; dst = W2T  + (size_t)(z - 16) * 16384; R = 128; }
  else             { src = We1 + (size_t)(z - 32) * 16384; dst = We1T + (size_t)(z - 32) * 16384; R = 128; }
  int r0 = blockIdx.x * 32, c0 = blockIdx.y * 32;
  if (r0 >= R) return;
  __shared__ float tile[32][33];
  int tx = tid & 31, ty = tid >> 5;
#pragma unroll
  for (int k = 0; k < 4; ++k)
    tile[ty + 8 * k][tx] = src[(size_t)(r0 + ty + 8 * k) * D_ + c0 + tx];
  __syncthreads();
#pragma unroll
  for (int k = 0; k < 4; ++k)
    dst[(size_t)(c0 + ty + 8 * k) * R + r0 + tx] = f2bu(tile[tx][ty + 8 * k]);
}

// ---------------- EA/EB precompute: eval-net pushed through init affine family ----
// block b: m = b/33, t = b%33 (t==32 -> svec row). 128 threads = e.
// EA[t][e] = sum_d tab[t][d]*We1[d][e] + be1[e]; EB[e] = sum_d svec[d]*We1[d][e]
__global__ __launch_bounds__(128) void eaprep_kernel(
    const float* init_table, const float* s_vec, const float* We1,
    const float* be1, const float* we2, float* EA2, float* EWB) {
  int b = blockIdx.x;
  int m = b / 33, t = b % 33;
  int e = threadIdx.x;
  const float* vec = (t < 32) ? &init_table[(size_t)(m * T_ + t) * D_]
                              : &s_vec[(size_t)m * D_];
  const float* w = &We1[(size_t)m * D_ * D_];
  float acc = 0.f;
#pragma unroll 8
  for (int d = 0; d < D_; ++d) acc = fmaf(vec[d], w[d * D_ + e], acc);
  if (t < 32) {
    // layout: EA2[m][p=e>>1][t][e&1] -> bank-safe per-lane gather by t
    EA2[m * 4096 + ((e >> 1) * 32 + t) * 2 + (e & 1)] = acc + be1[m * D_ + e];
  } else {
    EWB[(m * D_ + e) * 2 + 0] = acc;
    EWB[(m * D_ + e) * 2 + 1] = we2[m * D_ + e];
  }
}

// ---------------- counting sort of each layer's nodes by rule ----------------
__global__ __launch_bounds__(256) void rsort_kernel(const int* ridx, int* sorted,
                                                    int* starts, int* counts) {
  int l = blockIdx.x;
  __shared__ int cnt[R_], off[R_];
  int tid = threadIdx.x;
  if (tid < R_) cnt[tid] = 0;
  __syncthreads();
  for (int n = tid; n < NPL_; n += 256) atomicAdd(&cnt[ridx[l * NPL_ + n]], 1);
  __syncthreads();
  if (tid == 0) {
    int run = 0;
    for (int r = 0; r < R_; ++r) {
      off[r] = run; starts[l * R_ + r] = run; counts[l * R_ + r] = cnt[r];
      run += cnt[r];
    }
  }
  __syncthreads();
  for (int n = tid; n < NPL_; n += 256) {
    int r = ridx[l * NPL_ + n];
    int p = atomicAdd(&off[r], 1);
    sorted[l * NPL_ + p] = n;   // order within rule irrelevant: per-row math identical
  }
}

// ---------------- one DAG layer: rule-batched 2-layer MLP via MFMA ----------------
// grid (tile=128, r=8, m=2), block = 1 wave (64)
__global__ __launch_bounds__(64) void layer_kernel(int l,
    const int* thax, const float* sine, const int* par,
    const float* b1, const float* b2, const float* tweaks,
    const unsigned short* tab, const unsigned short* svec,
    const unsigned short* W1T, const unsigned short* W2T,
    const int* sorted, const int* starts, const int* counts,
    unsigned short* sd) {
  int tile = blockIdx.x, r = blockIdx.y, m = blockIdx.z;
  int cnt = counts[l * R_ + r];
  int base = tile * 16;
  if (base >= cnt) return;
  int start = starts[l * R_ + r];
  int lane = threadIdx.x;
  int l15 = lane & 15, l4 = lane >> 4;
  int valid = cnt - base; if (valid > 16) valid = 16;
  int loc = base + (l15 < valid ? l15 : valid - 1);        // clamp pad rows
  int node = sorted[l * NPL_ + start + loc];
  int p0 = par[(l * NPL_ + node) * 2 + 0];
  int p1 = par[(l * NPL_ + node) * 2 + 1];
  const unsigned short* w1b = &W1T[(size_t)(m * R_ + r) * D_ * 256];
  const unsigned short* w2b = &W2T[(size_t)(m * R_ + r) * D_ * D_];

  // preload all 8 A-chunks (hide gather latency ahead of MFMA burst)
  bf16x8 av[8];
#pragma unroll
  for (int kc = 0; kc < 8; ++kc) {
    int k = kc * 32 + l4 * 8;
    int p = (k < 128) ? p0 : p1;
    av[kc] = node_chunk(m, p, k & 127, tab, svec, sd, thax, sine);
  }
  f32x4 acch[8];
#pragma unroll
  for (int f = 0; f < 8; ++f) acch[f] = (f32x4){0.f, 0.f, 0.f, 0.f};
#pragma unroll
  for (int kc = 0; kc < 8; ++kc) {
    int k = kc * 32 + l4 * 8;
#pragma unroll
    for (int f = 0; f < 8; ++f) {
      bf16x8 b = ldb8(&w1b[(f * 16 + l15) * 256 + k]);
      acch[f] = __builtin_amdgcn_mfma_f32_16x16x32_bf16(av[kc], b, acch[f], 0, 0, 0);
    }
  }
  // C-layout -> A-layout round trip through swizzled LDS
  __shared__ unsigned short h_lds[16 * 128];
  const float* b1v = &b1[(m * R_ + r) * D_];
#pragma unroll
  for (int f = 0; f < 8; ++f) {
    int d = f * 16 + l15;
    float bb = b1v[d];
#pragma unroll
    for (int i = 0; i < 4; ++i) {
      int row = l4 * 4 + i;
      float h = acch[f][i] + bb;
      h = h > 0.f ? h : 0.f;
      h_lds[row * 128 + (d ^ ((row & 7) << 3))] = f2bu(h);
    }
  }
  __syncthreads();
  f32x4 acco[8];
#pragma unroll
  for (int f = 0; f < 8; ++f) acco[f] = (f32x4){0.f, 0.f, 0.f, 0.f};
#pragma unroll
  for (int kc = 0; kc < 4; ++kc) {
    int d0 = kc * 32 + l4 * 8;
    int row = l15;
    bf16x8 a2 = ldb8(&h_lds[row * 128 + (d0 ^ ((row & 7) << 3))]);
#pragma unroll
    for (int f = 0; f < 8; ++f) {
      bf16x8 b = ldb8(&w2b[(f * 16 + l15) * D_ + d0]);
      acco[f] = __builtin_amdgcn_mfma_f32_16x16x32_bf16(a2, b, acco[f], 0, 0, 0);
    }
  }
  float tw1 = tweaks[m * 2 + 1];
  const float* b2v = &b2[(m * R_ + r) * D_];
#pragma unroll
  for (int i = 0; i < 4; ++i) {
    int row = l4 * 4 + i;
    if (row < valid) {
      int nd = sorted[l * NPL_ + start + base + row];
      unsigned short* dst = &sd[(size_t)(m * ND_ + l * NPL_ + nd) * D_];
#pragma unroll
      for (int f = 0; f < 8; ++f) {
        int e = f * 16 + l15;
        dst[e] = f2bu(acco[f][i] + b2v[e] + tw1);
      }
    }
  }
}

// ---------------- init-node eval: analytical logit via EA/EB (pure f32 VALU) ----
// grid (512, 2), block 256: one node per thread
__global__ __launch_bounds__(256) void eval_init_kernel(
    const int* thax, const float* sine, const float* pos, const float* neg,
    const float* EA2, const float* EWB, const float* be2, const float* tweaks,
    float* pA, float* pB, float* pPok, float* pNok, float* pTp, float* pTn) {
  int m = blockIdx.y;
  __shared__ float lea[4096];   // [p=64][t=32][2]
  __shared__ float lwb[256];    // [e=128][{EB,we2}]
  __shared__ float red[6][4];
  int tid = threadIdx.x;
  for (int i = tid; i < 4096; i += 256) lea[i] = EA2[m * 4096 + i];
  if (tid < 256) lwb[tid] = EWB[m * 256 + tid];
  __syncthreads();
  int row = blockIdx.x * 256 + tid;
  int t = thax[row];
  float s = sine[row];
  float acc = 0.f;
#pragma unroll 8
  for (int p = 0; p < 64; ++p) {
    float2 ea = *(const float2*)&lea[(p * 32 + t) * 2];   // bank = 2t%32: free 2-way
    float4 wb = *(const float4*)&lwb[p * 4];              // uniform broadcast
    float x0 = fmaf(s, wb.x, ea.x); x0 = fmaxf(x0, 0.f);
    acc = fmaf(x0, wb.y, acc);
    float x1 = fmaf(s, wb.z, ea.y); x1 = fmaxf(x1, 0.f);
    acc = fmaf(x1, wb.w, acc);
  }
  float logit = acc + be2[m] + tweaks[m * 2 + 0];
  float p_ = pos[row], n_ = neg[row];
  float lse = log1pf(__expf(-fabsf(logit)));
  float v0 = p_ * (fmaxf(-logit, 0.f) + lse);     // pos * softplus(-logit)
  float v1 = n_ * (fmaxf(logit, 0.f) + lse);      // neg * softplus(logit)
  float v2 = logit >= 0.f ? p_ : 0.f;
  float v3 = logit < 0.f ? n_ : 0.f;
  float v[6] = {v0, v1, v2, v3, p_, n_};
#pragma unroll
  for (int mask = 1; mask < 64; mask <<= 1) {
#pragma unroll
    for (int q = 0; q < 6; ++q) v[q] += __shfl_xor(v[q], mask, 64);
  }
  int w = tid >> 6, lane = tid & 63;
  if (lane == 0) {
#pragma unroll
    for (int q = 0; q < 6; ++q) red[q][w] = v[q];
  }
  __syncthreads();
  if (tid == 0) {
    float t6[6];
#pragma unroll
    for (int q = 0; q < 6; ++q)
      t6[q] = red[q][0] + red[q][1] + red[q][2] + red[q][3];
    int slot = blockIdx.x;              // 0..511
    pA[m * PART_ + slot] = t6[0];
    pB[m * PART_ + slot] = t6[1];
    pPok[m * PART_ + slot] = t6[2];
    pNok[m * PART_ + slot] = t6[3];
    if (m == 0) { pTp[slot] = t6[4]; pTn[slot] = t6[5]; }
  }
}

// ---------------- deriv-node eval: MFMA path (8192 rows/model) ----------------
// grid (128, 2), block 256 = 4 waves x 16 rows
__global__ __launch_bounds__(256) void eval_deriv_kernel(
    const float* pos, const float* neg,
    const float* be1, const float* we2, const float* be2, const float* tweaks,
    const unsigned short* We1T, const unsigned short* sd,
    float* pA, float* pB, float* pPok, float* pNok, float* pTp, float* pTn) {
  int tile = blockIdx.x, m = blockIdx.y;
  int tid = threadIdx.x;
  int w = tid >> 6, lane = tid & 63;
  int l15 = lane & 15, l4 = lane >> 4;
  int rbase = tile * 64 + w * 16;      // deriv index base
  int arow = rbase + l15;

  bf16x8 a[4];
#pragma unroll
  for (int kc = 0; kc < 4; ++kc)
    a[kc] = ldb8(&sd[((size_t)m * ND_ + arow) * D_ + kc * 32 + l4 * 8]);

  f32x4 acc[8];
#pragma unroll
  for (int f = 0; f < 8; ++f) acc[f] = (f32x4){0.f, 0.f, 0.f, 0.f};
#pragma unroll
  for (int kc = 0; kc < 4; ++kc) {
#pragma unroll
    for (int f = 0; f < 8; ++f) {
      bf16x8 b = ldb8(&We1T[(m * D_ + f * 16 + l15) * D_ + kc * 32 + l4 * 8]);
      acc[f] = __builtin_amdgcn_mfma_f32_16x16x32_bf16(a[kc], b, acc[f], 0, 0, 0);
    }
  }
  float part[4] = {0.f, 0.f, 0.f, 0.f};
#pragma unroll
  for (int f = 0; f < 8; ++f) {
    int e = f * 16 + l15;
    float bb = be1[m * D_ + e];
    float wv = we2[m * D_ + e];
#pragma unroll
    for (int i = 0; i < 4; ++i) {
      float he = acc[f][i] + bb;
      he = he > 0.f ? he : 0.f;
      part[i] += he * wv;
    }
  }
#pragma unroll
  for (int mask = 1; mask < 16; mask <<= 1) {
#pragma unroll
    for (int i = 0; i < 4; ++i) part[i] += __shfl_xor(part[i], mask, 64);
  }
  __shared__ float red[6][16];
  if (l15 == 0) {
    float tw0 = tweaks[m * 2 + 0];
    float bev = be2[m];
    float sa = 0.f, sb = 0.f, spok = 0.f, snok = 0.f, stp = 0.f, stn = 0.f;
#pragma unroll
    for (int i = 0; i < 4; ++i) {
      int row = NI_ + rbase + l4 * 4 + i;
      float logit = part[i] + bev + tw0;
      float p = pos[row], ng = neg[row];
      float lse = log1pf(__expf(-fabsf(logit)));
      sa += p * (fmaxf(-logit, 0.f) + lse);
      sb += ng * (fmaxf(logit, 0.f) + lse);
      if (logit >= 0.f) spok += p; else snok += ng;
      stp += p; stn += ng;
    }
    int slot = w * 4 + l4;
    red[0][slot] = sa;   red[1][slot] = sb;
    red[2][slot] = spok; red[3][slot] = snok;
    red[4][slot] = stp;  red[5][slot] = stn;
  }
  __syncthreads();
  if (tid == 0) {
    float t6[6];
#pragma unroll
    for (int q = 0; q < 6; ++q) {
      float s = 0.f;
      for (int k = 0; k < 16; ++k) s += red[q][k];
      t6[q] = s;
    }
    int slot = 512 + tile;              // 512..639
    pA[m * PART_ + slot] = t6[0];
    pB[m * PART_ + slot] = t6[1];
    pPok[m * PART_ + slot] = t6[2];
    pNok[m * PART_ + slot] = t6[3];
    if (m == 0) { pTp[slot] = t6[4]; pTn[slot] = t6[5]; }
  }
}

// ---------------- deterministic final reduction ----------------
__global__ __launch_bounds__(256) void finalize_kernel(
    const float* pA, const float* pB, const float* pPok, const float* pNok,
    const float* pTp, const float* pTn, float* out) {
  __shared__ float red[256];
  __shared__ float totals[10];
  const float* srcs[10] = {pA, pA + PART_, pB, pB + PART_,
                           pPok, pPok + PART_, pNok, pNok + PART_,
                           pTp, pTn};
  int tid = threadIdx.x;
  for (int q = 0; q < 10; ++q) {
    float s = 0.f;
    for (int i = tid; i < PART_; i += 256) s += srcs[q][i];
    red[tid] = s;
    __syncthreads();
    if (tid == 0) {
      float t = 0.f;
      for (int k = 0; k < 256; ++k) t += red[k];
      totals[q] = t;
    }
    __syncthreads();
  }
  if (tid == 0) {
    float tp = totals[8], tn = totals[9];
    float pw = tn / tp;
    out[0] = pw * totals[0] + totals[2];    // loss m0
    out[1] = pw * totals[1] + totals[3];    // loss m1
    out[2] = totals[4]; out[3] = totals[5]; // posOK
    out[4] = totals[6]; out[5] = totals[7]; // negOK
    out[6] = tp; out[7] = tn;
  }
}

extern "C" void kernel_launch(void* const* d_in, const int* in_sizes, int n_in,
                              void* d_out, int out_size, void* d_ws, size_t ws_size,
                              hipStream_t stream) {
  const int*   thax = (const int*)d_in[0];
  const float* sine = (const float*)d_in[1];
  const int*   par  = (const int*)d_in[2];
  const int*   ridx = (const int*)d_in[3];
  const float* pos  = (const float*)d_in[4];
  const float* neg  = (const float*)d_in[5];
  const float* init_table = (const float*)d_in[6];
  const float* s_vec = (const float*)d_in[7];
  const float* W1 = (const float*)d_in[8];
  const float* b1 = (const float*)d_in[9];
  const float* W2 = (const float*)d_in[10];
  const float* b2 = (const float*)d_in[11];
  const float* tweaks = (const float*)d_in[12];
  const float* We1 = (const float*)d_in[13];
  const float* be1 = (const float*)d_in[14];
  const float* we2 = (const float*)d_in[15];
  const float* be2 = (const float*)d_in[16];

  char* ws = (char*)d_ws;
  unsigned short* W1T  = (unsigned short*)(ws + OFF_W1T);
  unsigned short* W2T  = (unsigned short*)(ws + OFF_W2T);
  unsigned short* We1T = (unsigned short*)(ws + OFF_WE1T);
  unsigned short* tab  = (unsigned short*)(ws + OFF_TAB);
  unsigned short* svec = (unsigned short*)(ws + OFF_SVEC);
  int* sorted = (int*)(ws + OFF_SORTED);
  int* starts = (int*)(ws + OFF_STARTS);
  int* counts = (int*)(ws + OFF_COUNTS);
  float* EA2  = (float*)(ws + OFF_EA2);
  float* EWB  = (float*)(ws + OFF_EWB);
  float* pA   = (float*)(ws + OFF_PA);
  float* pB   = (float*)(ws + OFF_PB);
  float* pPok = (float*)(ws + OFF_PPOK);
  float* pNok = (float*)(ws + OFF_PNOK);
  float* pTp  = (float*)(ws + OFF_PTP);
  float* pTn  = (float*)(ws + OFF_PTN);
  unsigned short* sd = (unsigned short*)(ws + OFF_STORE);

  prep_kernel<<<dim3(8, 4, 35), 256, 0, stream>>>(W1, W2, We1, init_table, s_vec,
                                                  W1T, W2T, We1T, tab, svec);
  eaprep_kernel<<<66, 128, 0, stream>>>(init_table, s_vec, We1, be1, we2, EA2, EWB);
  rsort_kernel<<<L_, 256, 0, stream>>>(ridx, sorted, starts, counts);
  for (int l = 0; l < L_; ++l) {
    layer_kernel<<<dim3(NPL_ / 16, R_, M_), 64, 0, stream>>>(
        l, thax, sine, par, b1, b2, tweaks, tab, svec, W1T, W2T,
        sorted, starts, counts, sd);
  }
  eval_init_kernel<<<dim3(NI_ / 256, M_), 256, 0, stream>>>(
      thax, sine, pos, neg, EA2, EWB, be2, tweaks, pA, pB, pPok, pNok, pTp, pTn);
  eval_deriv_kernel<<<dim3(ND_ / 64, M_), 256, 0, stream>>>(
      pos, neg, be1, we2, be2, tweaks, We1T, sd, pA, pB, pPok, pNok, pTp, pTn);
  finalize_kernel<<<1, 256, 0, stream>>>(pA, pB, pPok, pNok, pTp, pTn,
                                         (float*)d_out);
}

// Round 4
// 141.310 us; speedup vs baseline: 1.7593x; 1.3257x over previous
//
#include <hip/hip_runtime.h>
#include <hip/hip_bf16.h>

#define M_ 2
#define D_ 128
#define NI_ 131072
#define L_ 4
#define NPL_ 2048
#define R_ 8
#define T_ 32
#define N_ (NI_ + L_ * NPL_)   // 139264
#define ND_ (L_ * NPL_)        // 8192 deriv nodes
#define PART_ 640              // partial slots per model: 512 init + 128 deriv

typedef __bf16 bf16x8 __attribute__((ext_vector_type(8)));
typedef float f32x4 __attribute__((ext_vector_type(4)));

// ---- ws layout (bytes) ----
#define OFF_W1T    0u            // [M][R][128(d)][256(c)] bf16 = 1048576
#define OFF_W2T    1048576u      // [M][R][128(e)][128(d)] bf16 = 524288
#define OFF_WE1T   1572864u      // [M][128(e)][128(d)] bf16    = 65536
#define OFF_TAB    1638400u      // [M][T][128] bf16            = 16384
#define OFF_SVEC   1654784u      // [M][128] bf16               = 512
#define OFF_SORTED 1655296u      // [L][2048] int               = 32768
#define OFF_STARTS 1688064u      // [L][8] int (fast start)     = 128
#define OFF_CNTF   1688192u      // [L][8] int (fast count)     = 128
#define OFF_CNTA   1688320u      // [L][8] int (total count)    = 128
#define OFF_EA2    1688448u      // [M][64][32][2] f32          = 32768
#define OFF_EWB    1721216u      // [M][128][2] f32             = 2048
#define OFF_PA     1723264u      // [M][640] f32 = 5120
#define OFF_PB     1728384u
#define OFF_PPOK   1733504u
#define OFF_PNOK   1738624u
#define OFF_PTP    1743744u      // [640] f32 = 2560
#define OFF_PTN    1746304u
#define OFF_G      1748864u      // [M][R][2][33][128] f32 = 540672 (b1 folded into slot-a t<32)
#define OFF_STORE  2289536u     // [M][8192][128] bf16 = 4194304 ; end ~6.2MB

__device__ __forceinline__ unsigned short f2bu(float f) {
  unsigned int u = __float_as_uint(f);
  u += 0x7fffu + ((u >> 16) & 1u);        // RNE (finite values only)
  return (unsigned short)(u >> 16);
}
__device__ __forceinline__ bf16x8 ldb8(const unsigned short* p) {
  return *reinterpret_cast<const bf16x8*>(p);
}

// value of node `row` (global id), 8 consecutive dims starting at d0 (slow path).
__device__ __forceinline__ bf16x8 node_chunk(int m, int row, int d0,
    const unsigned short* tab, const unsigned short* svec,
    const unsigned short* sd, const int* thax, const float* sine) {
  if (row < NI_) {
    bf16x8 tv = ldb8(&tab[(m * T_ + thax[row]) * D_ + d0]);
    bf16x8 sv = ldb8(&svec[m * D_ + d0]);
    float sn = sine[row];
    bf16x8 r;
#pragma unroll
    for (int j = 0; j < 8; ++j)
      r[j] = (__bf16)((float)tv[j] + sn * (float)sv[j]);
    return r;
  }
  return ldb8(&sd[(size_t)(m * ND_ + (row - NI_)) * D_ + d0]);
}

// ================= mega-prep: transpose + G-tables + EA-tables + rsort =========
// job = blockIdx.x, 256 threads.
//   [0,512)    : W1 transpose tiles  (z=job/32, rblk=(job%32)/4, cblk=job%4)
//   [512,768)  : W2 transpose tiles
//   [768,800)  : We1 transpose tiles
//   800        : tab/svec bf16 convert
//   [801,1329) : gprep  (t=q/16, mr=q%16)  G tables for layer fast path
//   [1329,1363): eaprep (m=q/17, t=(q%17)*2+(tid>>7)) eval-init tables
//   [1363,1367): rsort  (l = q)  16-bucket counting sort (rule, hasDerivParent)
__global__ __launch_bounds__(256) void megaprep_kernel(
    const float* W1, const float* W2, const float* We1,
    const float* init_table, const float* s_vec,
    const float* b1, const float* be1, const float* we2,
    const int* ridx, const int* par,
    unsigned short* W1T, unsigned short* W2T, unsigned short* We1T,
    unsigned short* tab, unsigned short* svec,
    float* G, float* EA2, float* EWB,
    int* sorted, int* starts, int* cntF, int* cntA) {
  __shared__ float smem[1056];
  __shared__ int icnt[16], ioff[16];
  int job = blockIdx.x;
  int tid = threadIdx.x;

  if (job < 800) {                       // -------- transposes --------
    int z, rblk, cblk;
    if (job < 512)      { z = job >> 5;            rblk = (job & 31) >> 2; cblk = job & 3; }
    else if (job < 768) { int q = job - 512; z = 16 + (q >> 4); rblk = (q & 15) >> 2; cblk = q & 3; }
    else                { int q = job - 768; z = 32 + (q >> 4); rblk = (q & 15) >> 2; cblk = q & 3; }
    const float* src; unsigned short* dst; int R;
    if (z < 16)      { src = W1  + (size_t)z * 32768;        dst = W1T  + (size_t)z * 32768;        R = 256; }
    else if (z < 32) { src = W2  + (size_t)(z - 16) * 16384; dst = W2T  + (size_t)(z - 16) * 16384; R = 128; }
    else             { src = We1 + (size_t)(z - 32) * 16384; dst = We1T + (size_t)(z - 32) * 16384; R = 128; }
    int r0 = rblk * 32, c0 = cblk * 32;
    float (*tile)[33] = (float(*)[33])smem;
    int tx = tid & 31, ty = tid >> 5;
#pragma unroll
    for (int k = 0; k < 4; ++k)
      tile[ty + 8 * k][tx] = src[(size_t)(r0 + ty + 8 * k) * D_ + c0 + tx];
    __syncthreads();
#pragma unroll
    for (int k = 0; k < 4; ++k)
      dst[(size_t)(c0 + ty + 8 * k) * R + r0 + tx] = f2bu(tile[tx][ty + 8 * k]);
  } else if (job == 800) {               // -------- tab/svec convert --------
    for (int i = tid; i < 8448; i += 256) {
      if (i < 8192) tab[i] = f2bu(init_table[i]);
      else svec[i - 8192] = f2bu(s_vec[i - 8192]);
    }
  } else if (job < 1329) {               // -------- gprep: G[m][r][slot][t][e] --------
    int q = job - 801;
    int t = q / 16, mr = q & 15;         // t in [0,32], 32 == svec row
    int m = mr >> 3;
    int slot = tid >> 7, e = tid & 127;
    const float* vec = (t < 32) ? &init_table[(size_t)(m * T_ + t) * D_]
                                : &s_vec[(size_t)m * D_];
    if (tid < 128) smem[tid] = vec[tid];
    __syncthreads();
    const float* w = &W1[((size_t)mr * 256 + slot * 128) * D_];
    float acc = 0.f;
#pragma unroll 8
    for (int c = 0; c < 128; ++c) acc = fmaf(smem[c], w[c * D_ + e], acc);
    if (slot == 0 && t < 32) acc += b1[mr * D_ + e];   // fold b1 into slot-a rows
    G[((size_t)(mr * 2 + slot) * 33 + t) * D_ + e] = acc;
  } else if (job < 1363) {               // -------- eaprep: eval-init tables --------
    int q = job - 1329;
    int m = q / 17, t = (q % 17) * 2 + (tid >> 7);
    int e = tid & 127;
    if (t <= 32) {
      const float* vec = (t < 32) ? &init_table[(size_t)(m * T_ + t) * D_]
                                  : &s_vec[(size_t)m * D_];
      const float* w = &We1[(size_t)m * D_ * D_];
      float acc = 0.f;
#pragma unroll 8
      for (int d = 0; d < 128; ++d) acc = fmaf(vec[d], w[d * D_ + e], acc);
      if (t < 32) {
        EA2[m * 4096 + ((e >> 1) * 32 + t) * 2 + (e & 1)] = acc + be1[m * D_ + e];
      } else {
        EWB[(m * D_ + e) * 2 + 0] = acc;
        EWB[(m * D_ + e) * 2 + 1] = we2[m * D_ + e];
      }
    }
  } else {                               // -------- rsort: 16-bucket sort --------
    int l = job - 1363;
    if (tid < 16) icnt[tid] = 0;
    __syncthreads();
    for (int n = tid; n < NPL_; n += 256) {
      int r = ridx[l * NPL_ + n];
      int p0 = par[(l * NPL_ + n) * 2 + 0], p1 = par[(l * NPL_ + n) * 2 + 1];
      int slow = (p0 >= NI_ || p1 >= NI_) ? 1 : 0;
      atomicAdd(&icnt[r * 2 + slow], 1);
    }
    __syncthreads();
    if (tid == 0) {
      int run = 0;
      for (int b = 0; b < 16; ++b) { ioff[b] = run; run += icnt[b]; }
      for (int r = 0; r < R_; ++r) {
        starts[l * R_ + r] = ioff[2 * r];
        cntF[l * R_ + r] = icnt[2 * r];
        cntA[l * R_ + r] = icnt[2 * r] + icnt[2 * r + 1];
      }
    }
    __syncthreads();
    for (int n = tid; n < NPL_; n += 256) {
      int r = ridx[l * NPL_ + n];
      int p0 = par[(l * NPL_ + n) * 2 + 0], p1 = par[(l * NPL_ + n) * 2 + 1];
      int slow = (p0 >= NI_ || p1 >= NI_) ? 1 : 0;
      int p = atomicAdd(&ioff[r * 2 + slow], 1);
      sorted[l * NPL_ + p] = n;   // order within bucket irrelevant: row-independent math
    }
  }
}

// ================= one DAG layer =================
// grid (tile=128, r=8, z = m*2+role), block = 128 (2 waves, f-split).
// role 0: fast path (both parents init) — GEMM1 linearized via G tables.
// role 1: slow path (>=1 deriv parent) — original gather + MFMA GEMM1.
__global__ __launch_bounds__(128) void layer_kernel(int l,
    const int* thax, const float* sine, const int* par,
    const float* b1, const float* b2, const float* tweaks,
    const unsigned short* tab, const unsigned short* svec,
    const unsigned short* W1T, const unsigned short* W2T, const float* G,
    const int* sorted, const int* starts, const int* cntF, const int* cntA,
    unsigned short* sd) {
  int tile = blockIdx.x, r = blockIdx.y;
  int m = blockIdx.z >> 1, role = blockIdx.z & 1;
  int start = starts[l * R_ + r];
  int cF = cntF[l * R_ + r], cA = cntA[l * R_ + r];
  int base = tile * 16;
  int tid = threadIdx.x;
  int w = tid >> 6, lane = tid & 63;
  int l15 = lane & 15, l4 = lane >> 4;
  __shared__ unsigned short h_lds[16 * 128];

  float tw1 = tweaks[m * 2 + 1];
  const float* b2v = &b2[(m * R_ + r) * D_];
  const unsigned short* w2b = &W2T[(size_t)(m * R_ + r) * D_ * D_];

  if (role == 0) {                                  // ---------- fast ----------
    if (base >= cF) return;
    int loc = base + l15; if (loc >= cF) loc = cF - 1;
    int node = sorted[l * NPL_ + start + loc];
    int p0 = par[(l * NPL_ + node) * 2 + 0];
    int p1 = par[(l * NPL_ + node) * 2 + 1];
    int t0 = thax[p0], t1 = thax[p1];               // fast rows: p0,p1 < NI guaranteed
    float s0 = sine[p0], s1 = sine[p1];
    const float* Gm = &G[(size_t)(m * R_ + r) * 8448];
    const float* ra0 = &Gm[t0 * 128];               // Ga[t0] (+b1 folded)
    const float* rb0 = &Gm[(33 + t1) * 128];        // Gb[t1]
    const float* rs0 = &Gm[4096];                   // ga (svec slot a)
    const float* rt0 = &Gm[8320];                   // gb (svec slot b)

    f32x4 acc[4];
#pragma unroll
    for (int f = 0; f < 4; ++f) acc[f] = (f32x4){0.f, 0.f, 0.f, 0.f};
#pragma unroll
    for (int kc = 0; kc < 4; ++kc) {
      int d0 = kc * 32 + l4 * 8;
      float4 a0 = *(const float4*)&ra0[d0], a1 = *(const float4*)&ra0[d0 + 4];
      float4 b0 = *(const float4*)&rb0[d0], b1_ = *(const float4*)&rb0[d0 + 4];
      float4 u0 = *(const float4*)&rs0[d0], u1 = *(const float4*)&rs0[d0 + 4];
      float4 v0 = *(const float4*)&rt0[d0], v1 = *(const float4*)&rt0[d0 + 4];
      bf16x8 a2;
      float h;
      h = a0.x + b0.x + s0 * u0.x + s1 * v0.x; a2[0] = (__bf16)fmaxf(h, 0.f);
      h = a0.y + b0.y + s0 * u0.y + s1 * v0.y; a2[1] = (__bf16)fmaxf(h, 0.f);
      h = a0.z + b0.z + s0 * u0.z + s1 * v0.z; a2[2] = (__bf16)fmaxf(h, 0.f);
      h = a0.w + b0.w + s0 * u0.w + s1 * v0.w; a2[3] = (__bf16)fmaxf(h, 0.f);
      h = a1.x + b1_.x + s0 * u1.x + s1 * v1.x; a2[4] = (__bf16)fmaxf(h, 0.f);
      h = a1.y + b1_.y + s0 * u1.y + s1 * v1.y; a2[5] = (__bf16)fmaxf(h, 0.f);
      h = a1.z + b1_.z + s0 * u1.z + s1 * v1.z; a2[6] = (__bf16)fmaxf(h, 0.f);
      h = a1.w + b1_.w + s0 * u1.w + s1 * v1.w; a2[7] = (__bf16)fmaxf(h, 0.f);
#pragma unroll
      for (int f = 0; f < 4; ++f) {
        int fg = w * 4 + f;
        bf16x8 b = ldb8(&w2b[(fg * 16 + l15) * D_ + d0]);
        acc[f] = __builtin_amdgcn_mfma_f32_16x16x32_bf16(a2, b, acc[f], 0, 0, 0);
      }
    }
#pragma unroll
    for (int i = 0; i < 4; ++i) {
      int g = base + l4 * 4 + i;
      if (g < cF) {
        int nd = sorted[l * NPL_ + start + g];
        unsigned short* dst = &sd[(size_t)(m * ND_ + l * NPL_ + nd) * D_];
#pragma unroll
        for (int f = 0; f < 4; ++f) {
          int e = (w * 4 + f) * 16 + l15;
          dst[e] = f2bu(acc[f][i] + b2v[e] + tw1);
        }
      }
    }
  } else {                                          // ---------- slow ----------
    if (base + 16 <= cF || base >= cA) return;
    int loc = base + l15; if (loc >= cA) loc = cA - 1;
    int node = sorted[l * NPL_ + start + loc];
    int p0 = par[(l * NPL_ + node) * 2 + 0];
    int p1 = par[(l * NPL_ + node) * 2 + 1];
    const unsigned short* w1b = &W1T[(size_t)(m * R_ + r) * D_ * 256];

    bf16x8 av[8];
#pragma unroll
    for (int kc = 0; kc < 8; ++kc) {
      int k = kc * 32 + l4 * 8;
      int p = (k < 128) ? p0 : p1;
      av[kc] = node_chunk(m, p, k & 127, tab, svec, sd, thax, sine);
    }
    f32x4 acch[4];
#pragma unroll
    for (int f = 0; f < 4; ++f) acch[f] = (f32x4){0.f, 0.f, 0.f, 0.f};
#pragma unroll
    for (int kc = 0; kc < 8; ++kc) {
      int k = kc * 32 + l4 * 8;
#pragma unroll
      for (int f = 0; f < 4; ++f) {
        int fg = w * 4 + f;
        bf16x8 b = ldb8(&w1b[(fg * 16 + l15) * 256 + k]);
        acch[f] = __builtin_amdgcn_mfma_f32_16x16x32_bf16(av[kc], b, acch[f], 0, 0, 0);
      }
    }
    const float* b1v = &b1[(m * R_ + r) * D_];
#pragma unroll
    for (int f = 0; f < 4; ++f) {
      int d = (w * 4 + f) * 16 + l15;
      float bb = b1v[d];
#pragma unroll
      for (int i = 0; i < 4; ++i) {
        int row = l4 * 4 + i;
        float h = acch[f][i] + bb;
        h = h > 0.f ? h : 0.f;
        h_lds[row * 128 + (d ^ ((row & 7) << 3))] = f2bu(h);
      }
    }
    __syncthreads();
    f32x4 acco[4];
#pragma unroll
    for (int f = 0; f < 4; ++f) acco[f] = (f32x4){0.f, 0.f, 0.f, 0.f};
#pragma unroll
    for (int kc = 0; kc < 4; ++kc) {
      int d0 = kc * 32 + l4 * 8;
      bf16x8 a2 = ldb8(&h_lds[l15 * 128 + (d0 ^ ((l15 & 7) << 3))]);
#pragma unroll
      for (int f = 0; f < 4; ++f) {
        int fg = w * 4 + f;
        bf16x8 b = ldb8(&w2b[(fg * 16 + l15) * D_ + d0]);
        acco[f] = __builtin_amdgcn_mfma_f32_16x16x32_bf16(a2, b, acco[f], 0, 0, 0);
      }
    }
#pragma unroll
    for (int i = 0; i < 4; ++i) {
      int g = base + l4 * 4 + i;
      if (g >= cF && g < cA) {
        int nd = sorted[l * NPL_ + start + g];
        unsigned short* dst = &sd[(size_t)(m * ND_ + l * NPL_ + nd) * D_];
#pragma unroll
        for (int f = 0; f < 4; ++f) {
          int e = (w * 4 + f) * 16 + l15;
          dst[e] = f2bu(acco[f][i] + b2v[e] + tw1);
        }
      }
    }
  }
}

// ================= eval (init analytic + deriv MFMA fused) =================
// grid (640, m), block 256.  x<512: init (256 nodes/block); x>=512: deriv tile.
__global__ __launch_bounds__(256) void eval_kernel(
    const int* thax, const float* sine, const float* pos, const float* neg,
    const float* EA2, const float* EWB,
    const float* be1, const float* we2, const float* be2, const float* tweaks,
    const unsigned short* We1T, const unsigned short* sd,
    float* pA, float* pB, float* pPok, float* pNok, float* pTp, float* pTn) {
  __shared__ float sbuf[4096 + 256 + 96];
  float* red = sbuf + 4352;               // red[q*16 + slot]
  int m = blockIdx.y;
  int tid = threadIdx.x;
  int w = tid >> 6, lane = tid & 63;

  if (blockIdx.x < 512) {                 // ---------- init nodes ----------
    float* lea = sbuf;                    // [p=64][t=32][2]
    float* lwb = sbuf + 4096;             // [e=128][{EB,we2}]
    for (int i = tid; i < 4096; i += 256) lea[i] = EA2[m * 4096 + i];
    if (tid < 256) lwb[tid] = EWB[m * 256 + tid];
    __syncthreads();
    int row = blockIdx.x * 256 + tid;
    int t = thax[row];
    float s = sine[row];
    float acc = 0.f;
#pragma unroll 8
    for (int p = 0; p < 64; ++p) {
      float2 ea = *(const float2*)&lea[(p * 32 + t) * 2];   // bank 2t%32: free 2-way
      float4 wb = *(const float4*)&lwb[p * 4];              // uniform broadcast
      float x0 = fmaf(s, wb.x, ea.x); x0 = fmaxf(x0, 0.f);
      acc = fmaf(x0, wb.y, acc);
      float x1 = fmaf(s, wb.z, ea.y); x1 = fmaxf(x1, 0.f);
      acc = fmaf(x1, wb.w, acc);
    }
    float logit = acc + be2[m] + tweaks[m * 2 + 0];
    float p_ = pos[row], n_ = neg[row];
    float lse = log1pf(__expf(-fabsf(logit)));
    float v[6];
    v[0] = p_ * (fmaxf(-logit, 0.f) + lse);
    v[1] = n_ * (fmaxf(logit, 0.f) + lse);
    v[2] = logit >= 0.f ? p_ : 0.f;
    v[3] = logit < 0.f ? n_ : 0.f;
    v[4] = p_; v[5] = n_;
#pragma unroll
    for (int mask = 1; mask < 64; mask <<= 1) {
#pragma unroll
      for (int q = 0; q < 6; ++q) v[q] += __shfl_xor(v[q], mask, 64);
    }
    if (lane == 0) {
#pragma unroll
      for (int q = 0; q < 6; ++q) red[q * 16 + w] = v[q];
    }
    __syncthreads();
    if (tid == 0) {
      int slot = blockIdx.x;
      float t6[6];
#pragma unroll
      for (int q = 0; q < 6; ++q)
        t6[q] = red[q * 16 + 0] + red[q * 16 + 1] + red[q * 16 + 2] + red[q * 16 + 3];
      pA[m * PART_ + slot] = t6[0];
      pB[m * PART_ + slot] = t6[1];
      pPok[m * PART_ + slot] = t6[2];
      pNok[m * PART_ + slot] = t6[3];
      if (m == 0) { pTp[slot] = t6[4]; pTn[slot] = t6[5]; }
    }
  } else {                                // ---------- deriv nodes ----------
    int tile = blockIdx.x - 512;
    int l15 = lane & 15, l4 = lane >> 4;
    int rbase = tile * 64 + w * 16;
    int arow = rbase + l15;
    bf16x8 a[4];
#pragma unroll
    for (int kc = 0; kc < 4; ++kc)
      a[kc] = ldb8(&sd[((size_t)m * ND_ + arow) * D_ + kc * 32 + l4 * 8]);
    f32x4 acc[8];
#pragma unroll
    for (int f = 0; f < 8; ++f) acc[f] = (f32x4){0.f, 0.f, 0.f, 0.f};
#pragma unroll
    for (int kc = 0; kc < 4; ++kc) {
#pragma unroll
      for (int f = 0; f < 8; ++f) {
        bf16x8 b = ldb8(&We1T[(m * D_ + f * 16 + l15) * D_ + kc * 32 + l4 * 8]);
        acc[f] = __builtin_amdgcn_mfma_f32_16x16x32_bf16(a[kc], b, acc[f], 0, 0, 0);
      }
    }
    float part[4] = {0.f, 0.f, 0.f, 0.f};
#pragma unroll
    for (int f = 0; f < 8; ++f) {
      int e = f * 16 + l15;
      float bb = be1[m * D_ + e];
      float wv = we2[m * D_ + e];
#pragma unroll
      for (int i = 0; i < 4; ++i) {
        float he = acc[f][i] + bb;
        he = he > 0.f ? he : 0.f;
        part[i] += he * wv;
      }
    }
#pragma unroll
    for (int mask = 1; mask < 16; mask <<= 1) {
#pragma unroll
      for (int i = 0; i < 4; ++i) part[i] += __shfl_xor(part[i], mask, 64);
    }
    if (l15 == 0) {
      float tw0 = tweaks[m * 2 + 0];
      float bev = be2[m];
      float sa = 0.f, sb = 0.f, spok = 0.f, snok = 0.f, stp = 0.f, stn = 0.f;
#pragma unroll
      for (int i = 0; i < 4; ++i) {
        int row = NI_ + rbase + l4 * 4 + i;
        float logit = part[i] + bev + tw0;
        float p = pos[row], ng = neg[row];
        float lse = log1pf(__expf(-fabsf(logit)));
        sa += p * (fmaxf(-logit, 0.f) + lse);
        sb += ng * (fmaxf(logit, 0.f) + lse);
        if (logit >= 0.f) spok += p; else snok += ng;
        stp += p; stn += ng;
      }
      int slot = w * 4 + l4;
      red[0 * 16 + slot] = sa;   red[1 * 16 + slot] = sb;
      red[2 * 16 + slot] = spok; red[3 * 16 + slot] = snok;
      red[4 * 16 + slot] = stp;  red[5 * 16 + slot] = stn;
    }
    __syncthreads();
    if (tid == 0) {
      float t6[6];
#pragma unroll
      for (int q = 0; q < 6; ++q) {
        float s = 0.f;
        for (int k = 0; k < 16; ++k) s += red[q * 16 + k];
        t6[q] = s;
      }
      int slot = 512 + tile;
      pA[m * PART_ + slot] = t6[0];
      pB[m * PART_ + slot] = t6[1];
      pPok[m * PART_ + slot] = t6[2];
      pNok[m * PART_ + slot] = t6[3];
      if (m == 0) { pTp[slot] = t6[4]; pTn[slot] = t6[5]; }
    }
  }
}

// ---------------- deterministic final reduction ----------------
__global__ __launch_bounds__(256) void finalize_kernel(
    const float* pA, const float* pB, const float* pPok, const float* pNok,
    const float* pTp, const float* pTn, float* out) {
  __shared__ float red[256];
  __shared__ float totals[10];
  const float* srcs[10] = {pA, pA + PART_, pB, pB + PART_,
                           pPok, pPok + PART_, pNok, pNok + PART_,
                           pTp, pTn};
  int tid = threadIdx.x;
  for (int q = 0; q < 10; ++q) {
    float s = 0.f;
    for (int i = tid; i < PART_; i += 256) s += srcs[q][i];
    red[tid] = s;
    __syncthreads();
    if (tid == 0) {
      float t = 0.f;
      for (int k = 0; k < 256; ++k) t += red[k];
      totals[q] = t;
    }
    __syncthreads();
  }
  if (tid == 0) {
    float tp = totals[8], tn = totals[9];
    float pw = tn / tp;
    out[0] = pw * totals[0] + totals[2];    // loss m0
    out[1] = pw * totals[1] + totals[3];    // loss m1
    out[2] = totals[4]; out[3] = totals[5]; // posOK
    out[4] = totals[6]; out[5] = totals[7]; // negOK
    out[6] = tp; out[7] = tn;
  }
}

extern "C" void kernel_launch(void* const* d_in, const int* in_sizes, int n_in,
                              void* d_out, int out_size, void* d_ws, size_t ws_size,
                              hipStream_t stream) {
  const int*   thax = (const int*)d_in[0];
  const float* sine = (const float*)d_in[1];
  const int*   par  = (const int*)d_in[2];
  const int*   ridx = (const int*)d_in[3];
  const float* pos  = (const float*)d_in[4];
  const float* neg  = (const float*)d_in[5];
  const float* init_table = (const float*)d_in[6];
  const float* s_vec = (const float*)d_in[7];
  const float* W1 = (const float*)d_in[8];
  const float* b1 = (const float*)d_in[9];
  const float* W2 = (const float*)d_in[10];
  const float* b2 = (const float*)d_in[11];
  const float* tweaks = (const float*)d_in[12];
  const float* We1 = (const float*)d_in[13];
  const float* be1 = (const float*)d_in[14];
  const float* we2 = (const float*)d_in[15];
  const float* be2 = (const float*)d_in[16];

  char* ws = (char*)d_ws;
  unsigned short* W1T  = (unsigned short*)(ws + OFF_W1T);
  unsigned short* W2T  = (unsigned short*)(ws + OFF_W2T);
  unsigned short* We1T = (unsigned short*)(ws + OFF_WE1T);
  unsigned short* tab  = (unsigned short*)(ws + OFF_TAB);
  unsigned short* svec = (unsigned short*)(ws + OFF_SVEC);
  int* sorted = (int*)(ws + OFF_SORTED);
  int* starts = (int*)(ws + OFF_STARTS);
  int* cntF   = (int*)(ws + OFF_CNTF);
  int* cntA   = (int*)(ws + OFF_CNTA);
  float* EA2  = (float*)(ws + OFF_EA2);
  float* EWB  = (float*)(ws + OFF_EWB);
  float* pA   = (float*)(ws + OFF_PA);
  float* pB   = (float*)(ws + OFF_PB);
  float* pPok = (float*)(ws + OFF_PPOK);
  float* pNok = (float*)(ws + OFF_PNOK);
  float* pTp  = (float*)(ws + OFF_PTP);
  float* pTn  = (float*)(ws + OFF_PTN);
  float* G    = (float*)(ws + OFF_G);
  unsigned short* sd = (unsigned short*)(ws + OFF_STORE);

  megaprep_kernel<<<1367, 256, 0, stream>>>(
      W1, W2, We1, init_table, s_vec, b1, be1, we2, ridx, par,
      W1T, W2T, We1T, tab, svec, G, EA2, EWB, sorted, starts, cntF, cntA);
  for (int l = 0; l < L_; ++l) {
    layer_kernel<<<dim3(NPL_ / 16, R_, 4), 128, 0, stream>>>(
        l, thax, sine, par, b1, b2, tweaks, tab, svec, W1T, W2T, G,
        sorted, starts, cntF, cntA, sd);
  }
  eval_kernel<<<dim3(640, M_), 256, 0, stream>>>(
      thax, sine, pos, neg, EA2, EWB, be1, we2, be2, tweaks, We1T, sd,
      pA, pB, pPok, pNok, pTp, pTn);
  finalize_kernel<<<1, 256, 0, stream>>>(pA, pB, pPok, pNok, pTp, pTn,
                                         (float*)d_out);
}

// Round 6
// 99.264 us; speedup vs baseline: 2.5044x; 1.4236x over previous
//
#include <hip/hip_runtime.h>
#include <hip/hip_bf16.h>

#define M_ 2
#define D_ 128
#define NI_ 131072
#define L_ 4
#define NPL_ 2048
#define R_ 8
#define T_ 32
#define N_ (NI_ + L_ * NPL_)   // 139264
#define ND_ (L_ * NPL_)        // 8192 deriv nodes
#define PART_ 640              // partial slots per model: 512 init + 128 deriv
#define FT_ 80                 // fast tiles per rule (cap 1280 rows/rule; expect ~980)

typedef __bf16 bf16x8 __attribute__((ext_vector_type(8)));
typedef float f32x4 __attribute__((ext_vector_type(4)));

// ---- ws layout (bytes) ----
#define OFF_W1T    0u            // [M][R][128(d)][256(c)] bf16 = 1048576
#define OFF_W2T    1048576u      // [M][R][128(e)][128(d)] bf16 = 524288
#define OFF_WE1T   1572864u      // [M][128(e)][128(d)] bf16    = 65536
#define OFF_TAB    1638400u      // [M][T][128] bf16            = 16384
#define OFF_SVEC   1654784u      // [M][128] bf16               = 512
#define OFF_SORTED 1655296u      // [L][2048] int               = 32768
#define OFF_STARTS 1688064u      // [L][8] int (fast start)     = 128
#define OFF_CNTF   1688192u      // [L][8] int (fast count)     = 128
#define OFF_CNTA   1688320u      // [L][8] int (total count)    = 128
#define OFF_EA2    1688448u      // [M][64][32][2] f32          = 32768
#define OFF_EWB    1721216u      // [M][128][2] f32             = 2048
#define OFF_PA     1723264u      // [M][640] f32 = 5120
#define OFF_PB     1728384u
#define OFF_PPOK   1733504u
#define OFF_PNOK   1738624u
#define OFF_PTP    1743744u      // [640] f32 = 2560
#define OFF_PTN    1746304u
#define OFF_G      1748864u      // [M][R][2][33][128] f32 = 540672 (b1 folded into slot-a t<32)
#define OFF_STORE  2289536u      // [M][8192][128] bf16 = 4194304
#define OFF_FSG    6483840u      // [8] int  global fast starts
#define OFF_CFG    6483872u      // [8] int  global fast counts
#define OFF_FLIST  6483904u      // [8192] int global fast list ; end ~6.5MB

__device__ __forceinline__ unsigned short f2bu(float f) {
  unsigned int u = __float_as_uint(f);
  u += 0x7fffu + ((u >> 16) & 1u);        // RNE (finite values only)
  return (unsigned short)(u >> 16);
}
__device__ __forceinline__ bf16x8 ldb8(const unsigned short* p) {
  return *reinterpret_cast<const bf16x8*>(p);
}

// value of node `row` (global id), 8 dims from d0 (slow path only).
__device__ __forceinline__ bf16x8 node_chunk(int m, int row, int d0,
    const unsigned short* tab, const unsigned short* svec,
    const unsigned short* sd, const int* thax, const float* sine) {
  if (row < NI_) {
    bf16x8 tv = ldb8(&tab[(m * T_ + thax[row]) * D_ + d0]);
    bf16x8 sv = ldb8(&svec[m * D_ + d0]);
    float sn = sine[row];
    bf16x8 r;
#pragma unroll
    for (int j = 0; j < 8; ++j)
      r[j] = (__bf16)((float)tv[j] + sn * (float)sv[j]);
    return r;
  }
  return ldb8(&sd[(size_t)(m * ND_ + (row - NI_)) * D_ + d0]);
}

// ================= mega-prep =================
// jobs: [0,800) transposes; 800 tab/svec; [801,1329) gprep; [1329,1363) eaprep;
//       [1363,1367) per-layer 16-bucket rsort; 1367 global fast-list sort.
__global__ __launch_bounds__(256) void megaprep_kernel(
    const float* W1, const float* W2, const float* We1,
    const float* init_table, const float* s_vec,
    const float* b1, const float* be1, const float* we2,
    const int* ridx, const int* par,
    unsigned short* W1T, unsigned short* W2T, unsigned short* We1T,
    unsigned short* tab, unsigned short* svec,
    float* G, float* EA2, float* EWB,
    int* sorted, int* starts, int* cntF, int* cntA,
    int* fsg, int* cfg, int* fastlist) {
  __shared__ float smem[1056];
  __shared__ int icnt[16], ioff[16];
  int job = blockIdx.x;
  int tid = threadIdx.x;

  if (job < 800) {                       // -------- transposes --------
    int z, rblk, cblk;
    if (job < 512)      { z = job >> 5;            rblk = (job & 31) >> 2; cblk = job & 3; }
    else if (job < 768) { int q = job - 512; z = 16 + (q >> 4); rblk = (q & 15) >> 2; cblk = q & 3; }
    else                { int q = job - 768; z = 32 + (q >> 4); rblk = (q & 15) >> 2; cblk = q & 3; }
    const float* src; unsigned short* dst; int R;
    if (z < 16)      { src = W1  + (size_t)z * 32768;        dst = W1T  + (size_t)z * 32768;        R = 256; }
    else if (z < 32) { src = W2  + (size_t)(z - 16) * 16384; dst = W2T  + (size_t)(z - 16) * 16384; R = 128; }
    else             { src = We1 + (size_t)(z - 32) * 16384; dst = We1T + (size_t)(z - 32) * 16384; R = 128; }
    int r0 = rblk * 32, c0 = cblk * 32;
    float (*tile)[33] = (float(*)[33])smem;
    int tx = tid & 31, ty = tid >> 5;
#pragma unroll
    for (int k = 0; k < 4; ++k)
      tile[ty + 8 * k][tx] = src[(size_t)(r0 + ty + 8 * k) * D_ + c0 + tx];
    __syncthreads();
#pragma unroll
    for (int k = 0; k < 4; ++k)
      dst[(size_t)(c0 + ty + 8 * k) * R + r0 + tx] = f2bu(tile[tx][ty + 8 * k]);
  } else if (job == 800) {               // -------- tab/svec convert --------
    for (int i = tid; i < 8448; i += 256) {
      if (i < 8192) tab[i] = f2bu(init_table[i]);
      else svec[i - 8192] = f2bu(s_vec[i - 8192]);
    }
  } else if (job < 1329) {               // -------- gprep: G[m][r][slot][t][e] --------
    int q = job - 801;
    int t = q / 16, mr = q & 15;         // t in [0,32], 32 == svec row
    int m = mr >> 3;
    int slot = tid >> 7, e = tid & 127;
    const float* vec = (t < 32) ? &init_table[(size_t)(m * T_ + t) * D_]
                                : &s_vec[(size_t)m * D_];
    if (tid < 128) smem[tid] = vec[tid];
    __syncthreads();
    const float* w = &W1[((size_t)mr * 256 + slot * 128) * D_];
    float acc = 0.f;
#pragma unroll 8
    for (int c = 0; c < 128; ++c) acc = fmaf(smem[c], w[c * D_ + e], acc);
    if (slot == 0 && t < 32) acc += b1[mr * D_ + e];   // fold b1 into slot-a rows
    G[((size_t)(mr * 2 + slot) * 33 + t) * D_ + e] = acc;
  } else if (job < 1363) {               // -------- eaprep: eval-init tables --------
    int q = job - 1329;
    int m = q / 17, t = (q % 17) * 2 + (tid >> 7);
    int e = tid & 127;
    if (t <= 32) {
      const float* vec = (t < 32) ? &init_table[(size_t)(m * T_ + t) * D_]
                                  : &s_vec[(size_t)m * D_];
      const float* w = &We1[(size_t)m * D_ * D_];
      float acc = 0.f;
#pragma unroll 8
      for (int d = 0; d < 128; ++d) acc = fmaf(vec[d], w[d * D_ + e], acc);
      if (t < 32) {
        EA2[m * 4096 + ((e >> 1) * 32 + t) * 2 + (e & 1)] = acc + be1[m * D_ + e];
      } else {
        EWB[(m * D_ + e) * 2 + 0] = acc;
        EWB[(m * D_ + e) * 2 + 1] = we2[m * D_ + e];
      }
    }
  } else if (job < 1367) {               // -------- per-layer 16-bucket rsort --------
    int l = job - 1363;
    if (tid < 16) icnt[tid] = 0;
    __syncthreads();
    for (int n = tid; n < NPL_; n += 256) {
      int r = ridx[l * NPL_ + n];
      int p0 = par[(l * NPL_ + n) * 2 + 0], p1 = par[(l * NPL_ + n) * 2 + 1];
      int slow = (p0 >= NI_ || p1 >= NI_) ? 1 : 0;
      atomicAdd(&icnt[r * 2 + slow], 1);
    }
    __syncthreads();
    if (tid == 0) {
      int run = 0;
      for (int b = 0; b < 16; ++b) { ioff[b] = run; run += icnt[b]; }
      for (int r = 0; r < R_; ++r) {
        starts[l * R_ + r] = ioff[2 * r];
        cntF[l * R_ + r] = icnt[2 * r];
        cntA[l * R_ + r] = icnt[2 * r] + icnt[2 * r + 1];
      }
    }
    __syncthreads();
    for (int n = tid; n < NPL_; n += 256) {
      int r = ridx[l * NPL_ + n];
      int p0 = par[(l * NPL_ + n) * 2 + 0], p1 = par[(l * NPL_ + n) * 2 + 1];
      int slow = (p0 >= NI_ || p1 >= NI_) ? 1 : 0;
      int p = atomicAdd(&ioff[r * 2 + slow], 1);
      sorted[l * NPL_ + p] = n;   // order within bucket irrelevant: row-independent math
    }
  } else {                               // -------- global fast-list sort by rule --------
    if (tid < 8) icnt[tid] = 0;
    __syncthreads();
    for (int g = tid; g < ND_; g += 256) {
      int p0 = par[2 * g], p1 = par[2 * g + 1];
      if (p0 < NI_ && p1 < NI_) atomicAdd(&icnt[ridx[g]], 1);
    }
    __syncthreads();
    if (tid == 0) {
      int run = 0;
      for (int r = 0; r < R_; ++r) {
        ioff[r] = run; fsg[r] = run; cfg[r] = icnt[r]; run += icnt[r];
      }
    }
    __syncthreads();
    for (int g = tid; g < ND_; g += 256) {
      int p0 = par[2 * g], p1 = par[2 * g + 1];
      if (p0 < NI_ && p1 < NI_) {
        int p = atomicAdd(&ioff[ridx[g]], 1);
        fastlist[p] = g;     // g = l*NPL+n = deriv index
      }
    }
  }
}

// ================= main: all fast rows (all layers) + eval-init =================
// grid 2304 x 256. bid<1280: fast tile (m=bid/640, r=(bid%640)/80, tile=bid%80).
// bid>=1280: eval-init block (q=bid-1280, m=q>>9, xb=q&511).
__global__ __launch_bounds__(256) void main_kernel(
    const int* thax, const float* sine, const int* par,
    const float* pos, const float* neg,
    const float* b2, const float* tweaks,
    const float* G, const unsigned short* W2T,
    const float* EA2, const float* EWB, const float* be2,
    const int* fsg, const int* cfg, const int* fastlist,
    unsigned short* sd,
    float* pA, float* pB, float* pPok, float* pNok, float* pTp, float* pTn) {
  __shared__ float sbuf[4448];
  int bid = blockIdx.x;
  int tid = threadIdx.x;
  int w = tid >> 6, lane = tid & 63;

  if (bid < 1280) {                       // ---------- fast rows ----------
    int m = bid / 640, q = bid % 640;
    int r = q / 80, tile = q % 80;
    int cnt = cfg[r];
    int base = tile * 16;
    if (base >= cnt) return;
    unsigned short* h_lds = (unsigned short*)sbuf;       // [16][128] bf16
    int*   t0a  = (int*)(sbuf + 1024);
    int*   t1a  = t0a + 16;
    float* s0a  = (float*)(t1a + 16);
    float* s1a  = s0a + 16;
    int*   gida = (int*)(s1a + 16);
    if (tid < 16) {
      int loc = base + tid; if (loc >= cnt) loc = cnt - 1;
      int gid = fastlist[fsg[r] + loc];
      int p0 = par[2 * gid], p1 = par[2 * gid + 1];
      t0a[tid] = thax[p0]; s0a[tid] = sine[p0];
      t1a[tid] = thax[p1]; s1a[tid] = sine[p1];
      gida[tid] = gid;
    }
    __syncthreads();
    const float* Gm = &G[(size_t)(m * R_ + r) * 8448];
    {                                     // coop-build h (1 thread = row x 8 dims)
      int row = tid >> 4, seg = tid & 15, d0 = seg * 8;
      int t0 = t0a[row], t1 = t1a[row];
      float s0 = s0a[row], s1 = s1a[row];
      const float* pa = &Gm[t0 * 128 + d0];
      const float* pb = &Gm[(33 + t1) * 128 + d0];
      const float* pu = &Gm[4096 + d0];
      const float* pv = &Gm[8320 + d0];
      bf16x8 hv;
#pragma unroll
      for (int half = 0; half < 2; ++half) {
        float4 a = *(const float4*)(pa + half * 4);
        float4 b = *(const float4*)(pb + half * 4);
        float4 u = *(const float4*)(pu + half * 4);
        float4 v = *(const float4*)(pv + half * 4);
        hv[half * 4 + 0] = (__bf16)fmaxf(a.x + b.x + s0 * u.x + s1 * v.x, 0.f);
        hv[half * 4 + 1] = (__bf16)fmaxf(a.y + b.y + s0 * u.y + s1 * v.y, 0.f);
        hv[half * 4 + 2] = (__bf16)fmaxf(a.z + b.z + s0 * u.z + s1 * v.z, 0.f);
        hv[half * 4 + 3] = (__bf16)fmaxf(a.w + b.w + s0 * u.w + s1 * v.w, 0.f);
      }
      *(bf16x8*)&h_lds[row * 128 + (d0 ^ ((row & 7) << 3))] = hv;
    }
    __syncthreads();
    int l15 = lane & 15, l4 = lane >> 4;  // GEMM2: 4 waves x 2 f each
    const unsigned short* w2b = &W2T[(size_t)(m * R_ + r) * D_ * D_];
    f32x4 acc[2];
    acc[0] = (f32x4){0.f, 0.f, 0.f, 0.f};
    acc[1] = (f32x4){0.f, 0.f, 0.f, 0.f};
#pragma unroll
    for (int kc = 0; kc < 4; ++kc) {
      int d0 = kc * 32 + l4 * 8;
      bf16x8 a2 = ldb8(&h_lds[l15 * 128 + (d0 ^ ((l15 & 7) << 3))]);
#pragma unroll
      for (int f = 0; f < 2; ++f) {
        int fg = w * 2 + f;
        bf16x8 b = ldb8(&w2b[(fg * 16 + l15) * D_ + d0]);
        acc[f] = __builtin_amdgcn_mfma_f32_16x16x32_bf16(a2, b, acc[f], 0, 0, 0);
      }
    }
    float tw1 = tweaks[m * 2 + 1];
    const float* b2v = &b2[(m * R_ + r) * D_];
#pragma unroll
    for (int i = 0; i < 4; ++i) {
      int g = base + l4 * 4 + i;
      if (g < cnt) {
        int gid = gida[l4 * 4 + i];
        unsigned short* dst = &sd[(size_t)(m * ND_ + gid) * D_];
#pragma unroll
        for (int f = 0; f < 2; ++f) {
          int e = (w * 2 + f) * 16 + l15;
          dst[e] = f2bu(acc[f][i] + b2v[e] + tw1);
        }
      }
    }
  } else {                                // ---------- eval-init ----------
    int q = bid - 1280;
    int m = q >> 9, xb = q & 511;
    float* lea = sbuf;                    // [p=64][t=32][2]
    float* lwb = sbuf + 4096;             // [e=128][{EB,we2}]
    float* red = sbuf + 4352;             // [q*16 + slot]
    for (int i = tid; i < 4096; i += 256) lea[i] = EA2[m * 4096 + i];
    if (tid < 256) lwb[tid] = EWB[m * 256 + tid];
    __syncthreads();
    int row = xb * 256 + tid;
    int t = thax[row];
    float s = sine[row];
    float acc = 0.f;
#pragma unroll 8
    for (int p = 0; p < 64; ++p) {
      float2 ea = *(const float2*)&lea[(p * 32 + t) * 2];   // bank 2t%32: free 2-way
      float4 wb = *(const float4*)&lwb[p * 4];              // uniform broadcast
      float x0 = fmaf(s, wb.x, ea.x); x0 = fmaxf(x0, 0.f);
      acc = fmaf(x0, wb.y, acc);
      float x1 = fmaf(s, wb.z, ea.y); x1 = fmaxf(x1, 0.f);
      acc = fmaf(x1, wb.w, acc);
    }
    float logit = acc + be2[m] + tweaks[m * 2 + 0];
    float p_ = pos[row], n_ = neg[row];
    float lse = log1pf(__expf(-fabsf(logit)));
    float v[6];
    v[0] = p_ * (fmaxf(-logit, 0.f) + lse);
    v[1] = n_ * (fmaxf(logit, 0.f) + lse);
    v[2] = logit >= 0.f ? p_ : 0.f;
    v[3] = logit < 0.f ? n_ : 0.f;
    v[4] = p_; v[5] = n_;
#pragma unroll
    for (int mask = 1; mask < 64; mask <<= 1) {
#pragma unroll
      for (int k = 0; k < 6; ++k) v[k] += __shfl_xor(v[k], mask, 64);
    }
    if (lane == 0) {
#pragma unroll
      for (int k = 0; k < 6; ++k) red[k * 16 + w] = v[k];
    }
    __syncthreads();
    if (tid == 0) {
      float t6[6];
#pragma unroll
      for (int k = 0; k < 6; ++k)
        t6[k] = red[k * 16 + 0] + red[k * 16 + 1] + red[k * 16 + 2] + red[k * 16 + 3];
      pA[m * PART_ + xb] = t6[0];
      pB[m * PART_ + xb] = t6[1];
      pPok[m * PART_ + xb] = t6[2];
      pNok[m * PART_ + xb] = t6[3];
      if (m == 0) { pTp[xb] = t6[4]; pTn[xb] = t6[5]; }
    }
  }
}

// ================= slow rows of one layer (>=1 deriv parent) =================
// grid (8, 8, 2), block 128 (2 waves, f-split 4+4).
__global__ __launch_bounds__(128) void slow_kernel(int l,
    const int* thax, const float* sine, const int* par,
    const float* b1, const float* b2, const float* tweaks,
    const unsigned short* tab, const unsigned short* svec,
    const unsigned short* W1T, const unsigned short* W2T,
    const int* sorted, const int* starts, const int* cntF, const int* cntA,
    unsigned short* sd) {
  int tile = blockIdx.x, r = blockIdx.y, m = blockIdx.z;
  int cF = cntF[l * R_ + r];
  int cS = cntA[l * R_ + r] - cF;
  int base = tile * 16;
  if (base >= cS) return;
  int start = starts[l * R_ + r] + cF;
  int tid = threadIdx.x;
  int w = tid >> 6, lane = tid & 63;
  int l15 = lane & 15, l4 = lane >> 4;
  __shared__ unsigned short h_lds[16 * 128];

  int loc = base + l15; if (loc >= cS) loc = cS - 1;
  int node = sorted[l * NPL_ + start + loc];
  int p0 = par[(l * NPL_ + node) * 2 + 0];
  int p1 = par[(l * NPL_ + node) * 2 + 1];
  const unsigned short* w1b = &W1T[(size_t)(m * R_ + r) * D_ * 256];
  const unsigned short* w2b = &W2T[(size_t)(m * R_ + r) * D_ * D_];

  bf16x8 av[8];
#pragma unroll
  for (int kc = 0; kc < 8; ++kc) {
    int k = kc * 32 + l4 * 8;
    int p = (k < 128) ? p0 : p1;
    av[kc] = node_chunk(m, p, k & 127, tab, svec, sd, thax, sine);
  }
  f32x4 acch[4];
#pragma unroll
  for (int f = 0; f < 4; ++f) acch[f] = (f32x4){0.f, 0.f, 0.f, 0.f};
#pragma unroll
  for (int kc = 0; kc < 8; ++kc) {
    int k = kc * 32 + l4 * 8;
#pragma unroll
    for (int f = 0; f < 4; ++f) {
      int fg = w * 4 + f;
      bf16x8 b = ldb8(&w1b[(fg * 16 + l15) * 256 + k]);
      acch[f] = __builtin_amdgcn_mfma_f32_16x16x32_bf16(av[kc], b, acch[f], 0, 0, 0);
    }
  }
  const float* b1v = &b1[(m * R_ + r) * D_];
#pragma unroll
  for (int f = 0; f < 4; ++f) {
    int d = (w * 4 + f) * 16 + l15;
    float bb = b1v[d];
#pragma unroll
    for (int i = 0; i < 4; ++i) {
      int row = l4 * 4 + i;
      float h = acch[f][i] + bb;
      h = h > 0.f ? h : 0.f;
      h_lds[row * 128 + (d ^ ((row & 7) << 3))] = f2bu(h);
    }
  }
  __syncthreads();
  f32x4 acco[4];
#pragma unroll
  for (int f = 0; f < 4; ++f) acco[f] = (f32x4){0.f, 0.f, 0.f, 0.f};
#pragma unroll
  for (int kc = 0; kc < 4; ++kc) {
    int d0 = kc * 32 + l4 * 8;
    bf16x8 a2 = ldb8(&h_lds[l15 * 128 + (d0 ^ ((l15 & 7) << 3))]);
#pragma unroll
    for (int f = 0; f < 4; ++f) {
      int fg = w * 4 + f;
      bf16x8 b = ldb8(&w2b[(fg * 16 + l15) * D_ + d0]);
      acco[f] = __builtin_amdgcn_mfma_f32_16x16x32_bf16(a2, b, acco[f], 0, 0, 0);
    }
  }
  float tw1 = tweaks[m * 2 + 1];
  const float* b2v = &b2[(m * R_ + r) * D_];
#pragma unroll
  for (int i = 0; i < 4; ++i) {
    int g = base + l4 * 4 + i;
    if (g < cS) {
      int nd = sorted[l * NPL_ + start + g];
      unsigned short* dst = &sd[(size_t)(m * ND_ + l * NPL_ + nd) * D_];
#pragma unroll
      for (int f = 0; f < 4; ++f) {
        int e = (w * 4 + f) * 16 + l15;
        dst[e] = f2bu(acco[f][i] + b2v[e] + tw1);
      }
    }
  }
}

// ================= eval of deriv nodes (MFMA) =================
// grid (128, 2), block 256 = 4 waves x 16 rows
__global__ __launch_bounds__(256) void evald_kernel(
    const float* pos, const float* neg,
    const float* be1, const float* we2, const float* be2, const float* tweaks,
    const unsigned short* We1T, const unsigned short* sd,
    float* pA, float* pB, float* pPok, float* pNok, float* pTp, float* pTn) {
  int tile = blockIdx.x, m = blockIdx.y;
  int tid = threadIdx.x;
  int w = tid >> 6, lane = tid & 63;
  int l15 = lane & 15, l4 = lane >> 4;
  int rbase = tile * 64 + w * 16;
  int arow = rbase + l15;
  __shared__ float red[6][16];

  bf16x8 a[4];
#pragma unroll
  for (int kc = 0; kc < 4; ++kc)
    a[kc] = ldb8(&sd[((size_t)m * ND_ + arow) * D_ + kc * 32 + l4 * 8]);
  f32x4 acc[8];
#pragma unroll
  for (int f = 0; f < 8; ++f) acc[f] = (f32x4){0.f, 0.f, 0.f, 0.f};
#pragma unroll
  for (int kc = 0; kc < 4; ++kc) {
#pragma unroll
    for (int f = 0; f < 8; ++f) {
      bf16x8 b = ldb8(&We1T[(m * D_ + f * 16 + l15) * D_ + kc * 32 + l4 * 8]);
      acc[f] = __builtin_amdgcn_mfma_f32_16x16x32_bf16(a[kc], b, acc[f], 0, 0, 0);
    }
  }
  float part[4] = {0.f, 0.f, 0.f, 0.f};
#pragma unroll
  for (int f = 0; f < 8; ++f) {
    int e = f * 16 + l15;
    float bb = be1[m * D_ + e];
    float wv = we2[m * D_ + e];
#pragma unroll
    for (int i = 0; i < 4; ++i) {
      float he = acc[f][i] + bb;
      he = he > 0.f ? he : 0.f;
      part[i] += he * wv;
    }
  }
#pragma unroll
  for (int mask = 1; mask < 16; mask <<= 1) {
#pragma unroll
    for (int i = 0; i < 4; ++i) part[i] += __shfl_xor(part[i], mask, 64);
  }
  if (l15 == 0) {
    float tw0 = tweaks[m * 2 + 0];
    float bev = be2[m];
    float sa = 0.f, sb = 0.f, spok = 0.f, snok = 0.f, stp = 0.f, stn = 0.f;
#pragma unroll
    for (int i = 0; i < 4; ++i) {
      int row = NI_ + rbase + l4 * 4 + i;
      float logit = part[i] + bev + tw0;
      float p = pos[row], ng = neg[row];
      float lse = log1pf(__expf(-fabsf(logit)));
      sa += p * (fmaxf(-logit, 0.f) + lse);
      sb += ng * (fmaxf(logit, 0.f) + lse);
      if (logit >= 0.f) spok += p; else snok += ng;
      stp += p; stn += ng;
    }
    int slot = w * 4 + l4;
    red[0][slot] = sa;   red[1][slot] = sb;
    red[2][slot] = spok; red[3][slot] = snok;
    red[4][slot] = stp;  red[5][slot] = stn;
  }
  __syncthreads();
  if (tid == 0) {
    float t6[6];
#pragma unroll
    for (int q = 0; q < 6; ++q) {
      float s = 0.f;
      for (int k = 0; k < 16; ++k) s += red[q][k];
      t6[q] = s;
    }
    int slot = 512 + tile;
    pA[m * PART_ + slot] = t6[0];
    pB[m * PART_ + slot] = t6[1];
    pPok[m * PART_ + slot] = t6[2];
    pNok[m * PART_ + slot] = t6[3];
    if (m == 0) { pTp[slot] = t6[4]; pTn[slot] = t6[5]; }
  }
}

// ---------------- deterministic final reduction (shuffle tree) ----------------
__global__ __launch_bounds__(256) void finalize_kernel(
    const float* pA, const float* pB, const float* pPok, const float* pNok,
    const float* pTp, const float* pTn, float* out) {
  __shared__ float lred[10][4];
  const float* srcs[10] = {pA, pA + PART_, pB, pB + PART_,
                           pPok, pPok + PART_, pNok, pNok + PART_,
                           pTp, pTn};
  int tid = threadIdx.x;
  int w = tid >> 6, lane = tid & 63;
#pragma unroll
  for (int q = 0; q < 10; ++q) {
    float s = 0.f;
    for (int i = tid; i < PART_; i += 256) s += srcs[q][i];
#pragma unroll
    for (int mask = 1; mask < 64; mask <<= 1) s += __shfl_xor(s, mask, 64);
    if (lane == 0) lred[q][w] = s;
  }
  __syncthreads();
  if (tid == 0) {
    float totals[10];
#pragma unroll
    for (int q = 0; q < 10; ++q)
      totals[q] = lred[q][0] + lred[q][1] + lred[q][2] + lred[q][3];
    float tp = totals[8], tn = totals[9];
    float pw = tn / tp;
    out[0] = pw * totals[0] + totals[2];    // loss m0
    out[1] = pw * totals[1] + totals[3];    // loss m1
    out[2] = totals[4]; out[3] = totals[5]; // posOK
    out[4] = totals[6]; out[5] = totals[7]; // negOK
    out[6] = tp; out[7] = tn;
  }
}

extern "C" void kernel_launch(void* const* d_in, const int* in_sizes, int n_in,
                              void* d_out, int out_size, void* d_ws, size_t ws_size,
                              hipStream_t stream) {
  const int*   thax = (const int*)d_in[0];
  const float* sine = (const float*)d_in[1];
  const int*   par  = (const int*)d_in[2];
  const int*   ridx = (const int*)d_in[3];
  const float* pos  = (const float*)d_in[4];
  const float* neg  = (const float*)d_in[5];
  const float* init_table = (const float*)d_in[6];
  const float* s_vec = (const float*)d_in[7];
  const float* W1 = (const float*)d_in[8];
  const float* b1 = (const float*)d_in[9];
  const float* W2 = (const float*)d_in[10];
  const float* b2 = (const float*)d_in[11];
  const float* tweaks = (const float*)d_in[12];
  const float* We1 = (const float*)d_in[13];
  const float* be1 = (const float*)d_in[14];
  const float* we2 = (const float*)d_in[15];
  const float* be2 = (const float*)d_in[16];

  char* ws = (char*)d_ws;
  unsigned short* W1T  = (unsigned short*)(ws + OFF_W1T);
  unsigned short* W2T  = (unsigned short*)(ws + OFF_W2T);
  unsigned short* We1T = (unsigned short*)(ws + OFF_WE1T);
  unsigned short* tab  = (unsigned short*)(ws + OFF_TAB);
  unsigned short* svec = (unsigned short*)(ws + OFF_SVEC);
  int* sorted = (int*)(ws + OFF_SORTED);
  int* starts = (int*)(ws + OFF_STARTS);
  int* cntF   = (int*)(ws + OFF_CNTF);
  int* cntA   = (int*)(ws + OFF_CNTA);
  float* EA2  = (float*)(ws + OFF_EA2);
  float* EWB  = (float*)(ws + OFF_EWB);
  float* pA   = (float*)(ws + OFF_PA);
  float* pB   = (float*)(ws + OFF_PB);
  float* pPok = (float*)(ws + OFF_PPOK);
  float* pNok = (float*)(ws + OFF_PNOK);
  float* pTp  = (float*)(ws + OFF_PTP);
  float* pTn  = (float*)(ws + OFF_PTN);
  float* G    = (float*)(ws + OFF_G);
  unsigned short* sd = (unsigned short*)(ws + OFF_STORE);
  int* fsg      = (int*)(ws + OFF_FSG);
  int* cfg      = (int*)(ws + OFF_CFG);
  int* fastlist = (int*)(ws + OFF_FLIST);

  megaprep_kernel<<<1368, 256, 0, stream>>>(
      W1, W2, We1, init_table, s_vec, b1, be1, we2, ridx, par,
      W1T, W2T, We1T, tab, svec, G, EA2, EWB, sorted, starts, cntF, cntA,
      fsg, cfg, fastlist);
  main_kernel<<<2304, 256, 0, stream>>>(
      thax, sine, par, pos, neg, b2, tweaks, G, W2T, EA2, EWB, be2,
      fsg, cfg, fastlist, sd, pA, pB, pPok, pNok, pTp, pTn);
  for (int l = 1; l < L_; ++l) {          // layer 0 has no slow rows (parents < NI)
    slow_kernel<<<dim3(8, R_, M_), 128, 0, stream>>>(
        l, thax, sine, par, b1, b2, tweaks, tab, svec, W1T, W2T,
        sorted, starts, cntF, cntA, sd);
  }
  evald_kernel<<<dim3(128, M_), 256, 0, stream>>>(
      pos, neg, be1, we2, be2, tweaks, We1T, sd,
      pA, pB, pPok, pNok, pTp, pTn);
  finalize_kernel<<<1, 256, 0, stream>>>(pA, pB, pPok, pNok, pTp, pTn,
                                         (float*)d_out);
}